// Round 8
// baseline (283.736 us; speedup 1.0000x reference)
//
#include <hip/hip_runtime.h>
#include <cstdint>
#include <cstddef>

// B=16, N=1024, D=768, H=12, HS=64, L=2
// R14 changes vs R13 (277.9, passed):
//  - ADD gemmf_ln0: structural copy of the harness-proven gemmf_ln1
//    (non-template, uniform staging, 104KB LDS, identical loop), epilogue =
//    bias -> block-local LN -> swish -> write z1 bf16. Replaces
//    gemmf_256 (~45us) + lnswish (~20us) + one ~6us launch gap.
//  - Dispatches 7 -> 6. Everything else byte-identical to R13.
//
// ws layout (bytes): unchanged.
//  [0, 25165824)          slotA : xn_bf16 -> z1_bf16
//  [25165824, 50331648)   Vt    : gemm1 out
//  [50331648, 75497472)   slotX : x2_bf16 (circ out)
//  [75497472, 76677120)   W2t
//  [76677120, 79036416)   Wft

typedef __attribute__((ext_vector_type(8))) short bf16x8;
typedef __attribute__((ext_vector_type(4))) float f32x4;
typedef __attribute__((ext_vector_type(4))) unsigned short us4;

__device__ __forceinline__ unsigned short f2bf(float f) {
  unsigned int u = __builtin_bit_cast(unsigned int, f);
  u += 0x7FFFu + ((u >> 16) & 1u);
  return (unsigned short)(u >> 16);
}
__device__ __forceinline__ float bf2f(unsigned short u) {
  return __builtin_bit_cast(float, (unsigned int)u << 16);
}

__device__ __forceinline__ void g2l16(const void* g, void* l) {
  __builtin_amdgcn_global_load_lds(
      (const __attribute__((address_space(1))) unsigned int*)g,
      (__attribute__((address_space(3))) unsigned int*)l,
      16, 0, 0);
}

#define WAITB(n) asm volatile("s_waitcnt vmcnt(" #n ") lgkmcnt(0)\n\ts_barrier" ::: "memory")
#define BARX asm volatile("s_waitcnt lgkmcnt(0)\n\ts_barrier" ::: "memory")
#define BARV(n) asm volatile("s_waitcnt vmcnt(" #n ") lgkmcnt(0)\n\ts_barrier" ::: "memory")

// ---------------- pack kernel (merged) ----------------
__global__ __launch_bounds__(256) void pack_all(const float* __restrict__ Wv,
                                                const float* __restrict__ Wf,
                                                unsigned short* __restrict__ W2t,
                                                unsigned short* __restrict__ Wft) {
  int bid = blockIdx.x;
  if (bid < 2304) {
    int o = bid * 256 + threadIdx.x;
    int np = o / 768, d = o - np * 768;
    int h = np >> 6, k = np & 63;
    W2t[o] = f2bf(Wv[h * 49152 + d * 64 + k]);
  } else {
    int o = (bid - 2304) * 256 + threadIdx.x;
    int l = o / 589824, rem = o - l * 589824;
    int np = rem / 768, d = rem - np * 768;
    Wft[o] = f2bf(Wf[l * 589824 + d * 768 + np]);
  }
}

// ---------------- row kernels ----------------
__device__ __forceinline__ void wave_reduce2(float& s, float& s2) {
#pragma unroll
  for (int off = 32; off > 0; off >>= 1) {
    s += __shfl_down(s, off);
    s2 += __shfl_down(s2, off);
  }
  s = __shfl(s, 0);
  s2 = __shfl(s2, 0);
}

__global__ __launch_bounds__(256) void ln1_kernel(const float* __restrict__ x,
                                                  const float* __restrict__ sc,
                                                  const float* __restrict__ bi,
                                                  unsigned short* __restrict__ out) {
  int row = blockIdx.x * 4 + (threadIdx.x >> 6);
  int lane = threadIdx.x & 63;
  size_t base = (size_t)row * 768;
  float4 v[3];
#pragma unroll
  for (int j = 0; j < 3; ++j) v[j] = *(const float4*)(x + base + lane * 4 + j * 256);
  float s = 0.f, s2 = 0.f;
#pragma unroll
  for (int j = 0; j < 3; ++j) {
    s += v[j].x + v[j].y + v[j].z + v[j].w;
    s2 += v[j].x * v[j].x + v[j].y * v[j].y + v[j].z * v[j].z + v[j].w * v[j].w;
  }
  wave_reduce2(s, s2);
  float mu = s * (1.0f / 768.0f);
  float var = s2 * (1.0f / 768.0f) - mu * mu;
  float r = rsqrtf(var + 1e-6f);
#pragma unroll
  for (int j = 0; j < 3; ++j) {
    int d = lane * 4 + j * 256;
    float4 scv = *(const float4*)(sc + d);
    float4 biv = *(const float4*)(bi + d);
    us4 o;
    o[0] = f2bf((v[j].x - mu) * r * scv.x + biv.x);
    o[1] = f2bf((v[j].y - mu) * r * scv.y + biv.y);
    o[2] = f2bf((v[j].z - mu) * r * scv.z + biv.z);
    o[3] = f2bf((v[j].w - mu) * r * scv.w + biv.w);
    *(us4*)(out + base + d) = o;
  }
}

// ---------- 256x256 8-phase dense GEMM core (R8 verbatim) ----------
template <int K>
__device__ __forceinline__ void gemm256(const unsigned short* __restrict__ A,
                                        const unsigned short* __restrict__ Bt,
                                        int m0, int n0, unsigned short* lds,
                                        f32x4 acc[8][4]) {
  const int tid = threadIdx.x;
  const int lane = tid & 63;
  const int wid = tid >> 6;
  const int wm = (wid >> 2) << 6;
  const int wn = (wid & 3) << 5;
  const int fm = lane & 15, fq = lane >> 4;
  const int srow = tid >> 3;
  const int sslot = (tid & 7) ^ (srow & 7);
  const size_t abase = (size_t)(m0 + srow) * K + (sslot << 3);
  const size_t bbase = (size_t)(n0 + srow) * K + (sslot << 3);

  bf16x8 aq[4][2], bq[4][2];

#define STG_A(kt, bb, c)                                                     \
  g2l16(A + abase + (size_t)((c) << 6) * K + ((kt) << 6),                    \
        lds + ((bb) << 15) + ((c) << 12) + (tid << 3))
#define STG_B(kt, bb, c)                                                     \
  g2l16(Bt + bbase + (size_t)((c) << 6) * K + ((kt) << 6),                   \
        lds + ((bb) << 15) + 16384 + ((c) << 12) + (tid << 3))
#define LDA(bb, mh)                                                          \
  _Pragma("unroll") for (int mt = 0; mt < 4; ++mt) {                         \
    const unsigned short* p =                                                \
        lds + ((bb) << 15) + (wm + ((mh) << 7) + (mt << 4) + fm) * 64;       \
    _Pragma("unroll") for (int kk = 0; kk < 2; ++kk)                         \
      aq[mt][kk] = *(const bf16x8*)(p + ((((kk << 2) + fq) ^ (fm & 7)) << 3)); \
  }
#define LDB(bb, nh)                                                          \
  _Pragma("unroll") for (int nt = 0; nt < 2; ++nt) {                         \
    const unsigned short* p = lds + ((bb) << 15) + 16384 +                   \
                              (wn + ((nh) << 7) + (nt << 4) + fm) * 64;      \
    _Pragma("unroll") for (int kk = 0; kk < 2; ++kk)                         \
      bq[((nh) << 1) + nt][kk] =                                             \
          *(const bf16x8*)(p + ((((kk << 2) + fq) ^ (fm & 7)) << 3));        \
  }
#define MMX(mh, nh)                                                          \
  {                                                                          \
    __builtin_amdgcn_s_setprio(1);                                           \
    _Pragma("unroll") for (int mt = 0; mt < 4; ++mt)                         \
    _Pragma("unroll") for (int nt = 0; nt < 2; ++nt)                         \
    _Pragma("unroll") for (int kk = 0; kk < 2; ++kk)                         \
      acc[((mh) << 2) + mt][((nh) << 1) + nt] =                              \
          __builtin_amdgcn_mfma_f32_16x16x32_bf16(                           \
              aq[mt][kk], bq[((nh) << 1) + nt][kk],                          \
              acc[((mh) << 2) + mt][((nh) << 1) + nt], 0, 0, 0);             \
    __builtin_amdgcn_s_setprio(0);                                           \
  }

  constexpr int NT = K >> 6;
  STG_A(0, 0, 0); STG_A(0, 0, 1); STG_A(0, 0, 2); STG_A(0, 0, 3);
  STG_B(0, 0, 0); STG_B(0, 0, 1); STG_B(0, 0, 2); STG_B(0, 0, 3);
  STG_A(1, 1, 0); STG_A(1, 1, 1);
  STG_B(1, 1, 0); STG_B(1, 1, 1);
  BARV(4);

  for (int t = 0; t < (NT >> 1) - 1; ++t) {
    const int k1 = 2 * t + 1, k2 = 2 * t + 2, k3 = 2 * t + 3;
    LDA(0, 0); LDB(0, 0);
    STG_A(k1, 1, 2); STG_A(k1, 1, 3);
    MMX(0, 0); BARX;
    LDB(0, 1);
    STG_B(k1, 1, 2); STG_B(k1, 1, 3);
    MMX(0, 1); BARX;
    LDA(0, 1);
    STG_A(k2, 0, 0); STG_A(k2, 0, 1);
    MMX(1, 0); BARX;
    STG_B(k2, 0, 0); STG_B(k2, 0, 1);
    MMX(1, 1); BARV(4);
    LDA(1, 0); LDB(1, 0);
    STG_A(k2, 0, 2); STG_A(k2, 0, 3);
    MMX(0, 0); BARX;
    LDB(1, 1);
    STG_B(k2, 0, 2); STG_B(k2, 0, 3);
    MMX(0, 1); BARX;
    LDA(1, 1);
    STG_A(k3, 1, 0); STG_A(k3, 1, 1);
    MMX(1, 0); BARX;
    STG_B(k3, 1, 0); STG_B(k3, 1, 1);
    MMX(1, 1); BARV(4);
  }
  {
    const int k1 = NT - 1;
    LDA(0, 0); LDB(0, 0);
    STG_A(k1, 1, 2); STG_A(k1, 1, 3);
    MMX(0, 0); BARX;
    LDB(0, 1);
    STG_B(k1, 1, 2); STG_B(k1, 1, 3);
    MMX(0, 1); BARX;
    LDA(0, 1);
    MMX(1, 0); BARX;
    MMX(1, 1);
    BARV(0);
    LDA(1, 0); LDB(1, 0);
    MMX(0, 0); BARX;
    LDB(1, 1);
    MMX(0, 1); BARX;
    LDA(1, 1);
    MMX(1, 0); BARX;
    MMX(1, 1);
  }
#undef STG_A
#undef STG_B
#undef LDA
#undef LDB
#undef MMX
}

__device__ __forceinline__ void decode256(int bid, int& m0, int& n0) {
  int wg = (bid & 7) * 24 + (bid >> 3);
  int mi = wg / 3, ni = wg - mi * 3;
  m0 = mi << 8;
  n0 = ni << 8;
}

// GEMM1: xn @ W2t -> Vt[h][b*64+k][n] (bf16)
__global__ __launch_bounds__(512, 2) void gemm1_256(const unsigned short* __restrict__ A,
                                                    const unsigned short* __restrict__ W2t,
                                                    unsigned short* __restrict__ Vt) {
  extern __shared__ unsigned short lds[];
  f32x4 acc[8][4] = {};
  int m0, n0;
  decode256(blockIdx.x, m0, n0);
  gemm256<768>(A, W2t, m0, n0, lds, acc);
  const int lane = threadIdx.x & 63, wid = threadIdx.x >> 6;
  const int wm = (wid >> 2) << 6, wn = (wid & 3) << 5;
  const int fm = lane & 15, fq = lane >> 4;
#pragma unroll
  for (int ai = 0; ai < 8; ++ai) {
    int rowb = m0 + wm + ((ai >> 2) << 7) + ((ai & 3) << 4) + (fq << 2);
    int b = rowb >> 10, n = rowb & 1023;
#pragma unroll
    for (int nj = 0; nj < 4; ++nj) {
      int col = n0 + wn + ((nj >> 1) << 7) + ((nj & 1) << 4) + fm;
      int h = col >> 6, ck = col & 63;
      size_t off = ((size_t)h << 20) + (size_t)((b << 6) + ck) * 1024 + n;
      us4 v;
#pragma unroll
      for (int r = 0; r < 4; ++r) v[r] = f2bf(acc[ai][nj][r]);
      *(us4*)(Vt + off) = v;
    }
  }
}

// ---------- circ 256x256 8-phase (R8 verbatim) ----------
__global__ __launch_bounds__(512, 2) void circ256_kernel(const float* __restrict__ alpha,
                                                         const unsigned short* __restrict__ Vt,
                                                         const float* __restrict__ xin,
                                                         unsigned short* __restrict__ x2bf) {
  extern __shared__ unsigned short lds[];
  unsigned short* sAc = lds;          // 8*1288 = 10304 shorts
  unsigned short* sB = lds + 10304;   // 2*16384 shorts
  f32x4 acc[8][4] = {};

  int wg = (blockIdx.x & 7) * 24 + (blockIdx.x >> 3);
  int h = wg >> 4, tt = wg & 15;
  int m0 = (tt >> 2) << 8, n0 = (tt & 3) << 8;

  const int tid = threadIdx.x;
  const int lane = tid & 63, wid = tid >> 6;
  const int wm = (wid >> 2) << 6, wn = (wid & 3) << 5;
  const int fm = lane & 15, fq = lane >> 4;
  const int srow = tid >> 3;
  const int sslot = (tid & 7) ^ (srow & 7);

  const float* ah = alpha + (h << 10);
#pragma unroll
  for (int c = 0; c < 8; ++c)
    for (int u = tid; u < 1280; u += 512)
      sAc[c * 1288 + u] = f2bf(ah[(m0 - 769 - u - c) & 1023]);

  const unsigned short* Bt = Vt + ((size_t)h << 20);
  const size_t bbase = (size_t)(n0 + srow) * 1024 + (sslot << 3);

  bf16x8 aq[4][2], bq[4][2];

#define CSTG(kt, bb, c)                                                      \
  g2l16(Bt + bbase + (size_t)((c) << 6) * 1024 + ((kt) << 6),                \
        sB + ((bb) << 14) + ((c) << 12) + (tid << 3))
#define CLDA(kt, mh)                                                         \
  _Pragma("unroll") for (int mt = 0; mt < 4; ++mt)                           \
  _Pragma("unroll") for (int kk = 0; kk < 2; ++kk) {                         \
    int d_ = ((kt) << 6) + (kk << 5) + (fq << 3) + 255 -                     \
             (wm + ((mh) << 7) + (mt << 4) + fm);                            \
    int c_ = d_ & 7;                                                         \
    aq[mt][kk] = *(const bf16x8*)(sAc + c_ * 1288 + (d_ - c_));              \
  }
#define CLDB(bb, nh)                                                         \
  _Pragma("unroll") for (int nt = 0; nt < 2; ++nt) {                         \
    const unsigned short* p =                                                \
        sB + ((bb) << 14) + (wn + ((nh) << 7) + (nt << 4) + fm) * 64;        \
    _Pragma("unroll") for (int kk = 0; kk < 2; ++kk)                         \
      bq[((nh) << 1) + nt][kk] =                                             \
          *(const bf16x8*)(p + ((((kk << 2) + fq) ^ (fm & 7)) << 3));        \
  }
#define CMMX(mh, nh)                                                         \
  {                                                                          \
    __builtin_amdgcn_s_setprio(1);                                           \
    _Pragma("unroll") for (int mt = 0; mt < 4; ++mt)                         \
    _Pragma("unroll") for (int nt = 0; nt < 2; ++nt)                         \
    _Pragma("unroll") for (int kk = 0; kk < 2; ++kk)                         \
      acc[((mh) << 2) + mt][((nh) << 1) + nt] =                              \
          __builtin_amdgcn_mfma_f32_16x16x32_bf16(                           \
              aq[mt][kk], bq[((nh) << 1) + nt][kk],                          \
              acc[((mh) << 2) + mt][((nh) << 1) + nt], 0, 0, 0);             \
    __builtin_amdgcn_s_setprio(0);                                           \
  }

  CSTG(0, 0, 0); CSTG(0, 0, 1); CSTG(0, 0, 2); CSTG(0, 0, 3);
  CSTG(1, 1, 0); CSTG(1, 1, 1);
  BARV(2);

  for (int it = 0; it < 7; ++it) {
    const int k0 = 2 * it, k1 = 2 * it + 1, k2 = 2 * it + 2, k3 = 2 * it + 3;
    CLDA(k0, 0); CLDB(0, 0);
    CSTG(k1, 1, 2);
    CMMX(0, 0); BARX;
    CLDB(0, 1);
    CSTG(k1, 1, 3);
    CMMX(0, 1); BARX;
    CLDA(k0, 1);
    CSTG(k2, 0, 0);
    CMMX(1, 0); BARX;
    CSTG(k2, 0, 1);
    CMMX(1, 1); BARV(2);
    CLDA(k1, 0); CLDB(1, 0);
    CSTG(k2, 0, 2);
    CMMX(0, 0); BARX;
    CLDB(1, 1);
    CSTG(k2, 0, 3);
    CMMX(0, 1); BARX;
    CLDA(k1, 1);
    CSTG(k3, 1, 0);
    CMMX(1, 0); BARX;
    CSTG(k3, 1, 1);
    CMMX(1, 1); BARV(2);
  }
  CLDA(14, 0); CLDB(0, 0);
  CSTG(15, 1, 2);
  CMMX(0, 0); BARX;
  CLDB(0, 1);
  CSTG(15, 1, 3);
  CMMX(0, 1); BARX;
  CLDA(14, 1);
  CMMX(1, 0); BARX;
  CMMX(1, 1);
  BARV(0);
  CLDA(15, 0); CLDB(1, 0);
  CMMX(0, 0); BARX;
  CLDB(1, 1);
  CMMX(0, 1); BARX;
  CLDA(15, 1);
  CMMX(1, 0); BARX;
  CMMX(1, 1);
#undef CSTG
#undef CLDA
#undef CLDB
#undef CMMX

#pragma unroll
  for (int ai = 0; ai < 8; ++ai) {
    int i = m0 + wm + ((ai >> 2) << 7) + ((ai & 3) << 4) + (fq << 2);
#pragma unroll
    for (int nj = 0; nj < 4; ++nj) {
      int col = n0 + wn + ((nj >> 1) << 7) + ((nj & 1) << 4) + fm;
      int b = col >> 6, k = col & 63;
      size_t off = ((size_t)(b << 10) + i) * 768 + (h << 6) + k;
#pragma unroll
      for (int r = 0; r < 4; ++r) {
        float val = acc[ai][nj][r] + xin[off + (size_t)r * 768];
        x2bf[off + (size_t)r * 768] = f2bf(val);
      }
    }
  }
}

// ---------- fused FFN layer-0: GEMM + bias + LN + swish -> z1 bf16 ----------
// Structural copy of gemmf_ln1 (harness-proven R13): non-template, uniform
// staging (every thread 7 g2l16/stage; waves 4-7 duplicate A loads).
// 64x768 full-row tile, 8 waves x 96 cols, BK=32 2-buffer, 104KB LDS,
// grid 256 = one round at 1 block/CU.
__global__ __launch_bounds__(512, 2) void gemmf_ln0(
    const unsigned short* __restrict__ A,
    const unsigned short* __restrict__ Wt,
    const float* __restrict__ bias,
    const float* __restrict__ sc,
    const float* __restrict__ bi,
    unsigned short* __restrict__ outp) {
  extern __shared__ unsigned short lds[];
  unsigned short* sA = lds;          // 2 * 2048 shorts (8KB)
  unsigned short* sB = lds + 4096;   // 2 * 24576 shorts (96KB)
  float* fst = (float*)lds;          // stats overlay on sA after drain

  f32x4 acc[4][6] = {};
  int bid = blockIdx.x;
  int p = ((bid & 7) << 5) + (bid >> 3);   // bijective XCD swizzle
  const int m0 = p << 6;

  const int tid = threadIdx.x;
  const int lane = tid & 63;
  const int wid = tid >> 6;
  const int fm = lane & 15, fq = lane >> 4;
  const int wc0 = wid * 96;
  const int brow = tid >> 2;
  const int cg = tid & 3;
  const size_t wbase = (size_t)brow * 768 + ((cg ^ ((brow >> 1) & 3)) << 3);
  const int t2 = tid & 255;
  const int ar = t2 >> 2;
  const size_t abase = (size_t)(m0 + ar) * 768 + ((cg ^ ((ar >> 1) & 3)) << 3);

#define FSTG(step, buf)                                                      \
  {                                                                          \
    int k0_ = (step) << 5;                                                   \
    _Pragma("unroll") for (int c = 0; c < 6; ++c)                            \
      g2l16(Wt + wbase + c * 98304 + k0_,                                    \
            sB + (buf) * 24576 + c * 4096 + (tid << 3));                     \
    g2l16(A + abase + k0_, sA + (buf) * 2048 + (t2 << 3));                   \
  }
#define FCOMP(buf)                                                           \
  {                                                                          \
    bf16x8 aq[4], bq[6];                                                     \
    _Pragma("unroll") for (int mt = 0; mt < 4; ++mt) {                       \
      int ra = (mt << 4) + fm;                                               \
      aq[mt] = *(const bf16x8*)(sA + (buf) * 2048 + (ra << 5) +              \
                                ((fq ^ ((ra >> 1) & 3)) << 3));              \
    }                                                                        \
    _Pragma("unroll") for (int nt = 0; nt < 6; ++nt) {                       \
      int rb = wc0 + (nt << 4) + fm;                                         \
      bq[nt] = *(const bf16x8*)(sB + (buf) * 24576 + (rb << 5) +             \
                                ((fq ^ ((rb >> 1) & 3)) << 3));              \
    }                                                                        \
    __builtin_amdgcn_s_setprio(1);                                           \
    _Pragma("unroll") for (int mt = 0; mt < 4; ++mt)                         \
    _Pragma("unroll") for (int nt = 0; nt < 6; ++nt)                         \
      acc[mt][nt] = __builtin_amdgcn_mfma_f32_16x16x32_bf16(                 \
          aq[mt], bq[nt], acc[mt][nt], 0, 0, 0);                             \
    __builtin_amdgcn_s_setprio(0);                                           \
  }

  FSTG(0, 0);
  for (int it = 0; it < 24; ++it) {
    WAITB(0);
    if (it < 23) FSTG(it + 1, (it + 1) & 1);
    FCOMP(it & 1);
  }
  __syncthreads();

  float bc[6];
#pragma unroll
  for (int nt = 0; nt < 6; ++nt) bc[nt] = bias[wc0 + (nt << 4) + fm];
#pragma unroll
  for (int mt = 0; mt < 4; ++mt)
#pragma unroll
    for (int nt = 0; nt < 6; ++nt)
#pragma unroll
      for (int r = 0; r < 4; ++r) acc[mt][nt][r] += bc[nt];

  float s[4][4], s2[4][4];
#pragma unroll
  for (int mt = 0; mt < 4; ++mt)
#pragma unroll
    for (int r = 0; r < 4; ++r) {
      float a = 0.f, b2 = 0.f;
#pragma unroll
      for (int nt = 0; nt < 6; ++nt) {
        float v = acc[mt][nt][r];
        a += v;
        b2 += v * v;
      }
      s[mt][r] = a;
      s2[mt][r] = b2;
    }
#pragma unroll
  for (int off = 1; off <= 8; off <<= 1)
#pragma unroll
    for (int mt = 0; mt < 4; ++mt)
#pragma unroll
      for (int r = 0; r < 4; ++r) {
        s[mt][r] += __shfl_xor(s[mt][r], off);
        s2[mt][r] += __shfl_xor(s2[mt][r], off);
      }
  if (fm == 0) {
#pragma unroll
    for (int mt = 0; mt < 4; ++mt)
#pragma unroll
      for (int r = 0; r < 4; ++r) {
        int row = (mt << 4) + (fq << 2) + r;
        fst[wid * 64 + row] = s[mt][r];
        fst[512 + wid * 64 + row] = s2[mt][r];
      }
  }
  __syncthreads();
  if (tid < 64) {
    float ts = 0.f, ts2 = 0.f;
#pragma unroll
    for (int w = 0; w < 8; ++w) {
      ts += fst[w * 64 + tid];
      ts2 += fst[512 + w * 64 + tid];
    }
    float mu = ts * (1.0f / 768.0f);
    float var = ts2 * (1.0f / 768.0f) - mu * mu;
    fst[1024 + tid] = mu;
    fst[1088 + tid] = rsqrtf(var + 1e-6f);
  }
  __syncthreads();

  float scv[6], biv[6];
#pragma unroll
  for (int nt = 0; nt < 6; ++nt) {
    scv[nt] = sc[wc0 + (nt << 4) + fm];
    biv[nt] = bi[wc0 + (nt << 4) + fm];
  }
#pragma unroll
  for (int mt = 0; mt < 4; ++mt)
#pragma unroll
    for (int r = 0; r < 4; ++r) {
      int row = (mt << 4) + (fq << 2) + r;
      float mu = fst[1024 + row];
      float rr = fst[1088 + row];
      size_t rg = (size_t)(m0 + row) * 768;
#pragma unroll
      for (int nt = 0; nt < 6; ++nt) {
        int col = wc0 + (nt << 4) + fm;
        float z = (acc[mt][nt][r] - mu) * rr * scv[nt] + biv[nt];
        outp[rg + col] = f2bf(z / (1.0f + __expf(-z)));
      }
    }
#undef FSTG
#undef FCOMP
}

// ---------- fused FFN layer-1: GEMM + bias + LN + swish + residual +
// log_cosh -> f32 out (R13 verbatim, harness-proven) ----------
__global__ __launch_bounds__(512, 2) void gemmf_ln1(
    const unsigned short* __restrict__ A,
    const unsigned short* __restrict__ Wt,
    const float* __restrict__ bias,
    const float* __restrict__ sc,
    const float* __restrict__ bi,
    const unsigned short* __restrict__ x2,
    float* __restrict__ outp) {
  extern __shared__ unsigned short lds[];
  unsigned short* sA = lds;          // 2 * 2048 shorts (8KB)
  unsigned short* sB = lds + 4096;   // 2 * 24576 shorts (96KB)
  float* fst = (float*)lds;          // stats overlay on sA after drain

  f32x4 acc[4][6] = {};
  int bid = blockIdx.x;
  int p = ((bid & 7) << 5) + (bid >> 3);   // bijective XCD swizzle
  const int m0 = p << 6;

  const int tid = threadIdx.x;
  const int lane = tid & 63;
  const int wid = tid >> 6;
  const int fm = lane & 15, fq = lane >> 4;
  const int wc0 = wid * 96;
  const int brow = tid >> 2;
  const int cg = tid & 3;
  const size_t wbase = (size_t)brow * 768 + ((cg ^ ((brow >> 1) & 3)) << 3);
  const int t2 = tid & 255;
  const int ar = t2 >> 2;
  const size_t abase = (size_t)(m0 + ar) * 768 + ((cg ^ ((ar >> 1) & 3)) << 3);

#define FSTG(step, buf)                                                      \
  {                                                                          \
    int k0_ = (step) << 5;                                                   \
    _Pragma("unroll") for (int c = 0; c < 6; ++c)                            \
      g2l16(Wt + wbase + c * 98304 + k0_,                                    \
            sB + (buf) * 24576 + c * 4096 + (tid << 3));                     \
    g2l16(A + abase + k0_, sA + (buf) * 2048 + (t2 << 3));                   \
  }
#define FCOMP(buf)                                                           \
  {                                                                          \
    bf16x8 aq[4], bq[6];                                                     \
    _Pragma("unroll") for (int mt = 0; mt < 4; ++mt) {                       \
      int ra = (mt << 4) + fm;                                               \
      aq[mt] = *(const bf16x8*)(sA + (buf) * 2048 + (ra << 5) +              \
                                ((fq ^ ((ra >> 1) & 3)) << 3));              \
    }                                                                        \
    _Pragma("unroll") for (int nt = 0; nt < 6; ++nt) {                       \
      int rb = wc0 + (nt << 4) + fm;                                         \
      bq[nt] = *(const bf16x8*)(sB + (buf) * 24576 + (rb << 5) +             \
                                ((fq ^ ((rb >> 1) & 3)) << 3));              \
    }                                                                        \
    __builtin_amdgcn_s_setprio(1);                                           \
    _Pragma("unroll") for (int mt = 0; mt < 4; ++mt)                         \
    _Pragma("unroll") for (int nt = 0; nt < 6; ++nt)                         \
      acc[mt][nt] = __builtin_amdgcn_mfma_f32_16x16x32_bf16(                 \
          aq[mt], bq[nt], acc[mt][nt], 0, 0, 0);                             \
    __builtin_amdgcn_s_setprio(0);                                           \
  }

  FSTG(0, 0);
  for (int it = 0; it < 24; ++it) {
    WAITB(0);
    if (it < 23) FSTG(it + 1, (it + 1) & 1);
    FCOMP(it & 1);
  }
  __syncthreads();

  float bc[6];
#pragma unroll
  for (int nt = 0; nt < 6; ++nt) bc[nt] = bias[wc0 + (nt << 4) + fm];
#pragma unroll
  for (int mt = 0; mt < 4; ++mt)
#pragma unroll
    for (int nt = 0; nt < 6; ++nt)
#pragma unroll
      for (int r = 0; r < 4; ++r) acc[mt][nt][r] += bc[nt];

  float s[4][4], s2[4][4];
#pragma unroll
  for (int mt = 0; mt < 4; ++mt)
#pragma unroll
    for (int r = 0; r < 4; ++r) {
      float a = 0.f, b2 = 0.f;
#pragma unroll
      for (int nt = 0; nt < 6; ++nt) {
        float v = acc[mt][nt][r];
        a += v;
        b2 += v * v;
      }
      s[mt][r] = a;
      s2[mt][r] = b2;
    }
#pragma unroll
  for (int off = 1; off <= 8; off <<= 1)
#pragma unroll
    for (int mt = 0; mt < 4; ++mt)
#pragma unroll
      for (int r = 0; r < 4; ++r) {
        s[mt][r] += __shfl_xor(s[mt][r], off);
        s2[mt][r] += __shfl_xor(s2[mt][r], off);
      }
  if (fm == 0) {
#pragma unroll
    for (int mt = 0; mt < 4; ++mt)
#pragma unroll
      for (int r = 0; r < 4; ++r) {
        int row = (mt << 4) + (fq << 2) + r;
        fst[wid * 64 + row] = s[mt][r];
        fst[512 + wid * 64 + row] = s2[mt][r];
      }
  }
  __syncthreads();
  if (tid < 64) {
    float ts = 0.f, ts2 = 0.f;
#pragma unroll
    for (int w = 0; w < 8; ++w) {
      ts += fst[w * 64 + tid];
      ts2 += fst[512 + w * 64 + tid];
    }
    float mu = ts * (1.0f / 768.0f);
    float var = ts2 * (1.0f / 768.0f) - mu * mu;
    fst[1024 + tid] = mu;
    fst[1088 + tid] = rsqrtf(var + 1e-6f);
  }
  __syncthreads();

  float scv[6], biv[6];
#pragma unroll
  for (int nt = 0; nt < 6; ++nt) {
    scv[nt] = sc[wc0 + (nt << 4) + fm];
    biv[nt] = bi[wc0 + (nt << 4) + fm];
  }
#pragma unroll
  for (int mt = 0; mt < 4; ++mt)
#pragma unroll
    for (int r = 0; r < 4; ++r) {
      int row = (mt << 4) + (fq << 2) + r;
      float mu = fst[1024 + row];
      float rr = fst[1088 + row];
      size_t rg = (size_t)(m0 + row) * 768;
#pragma unroll
      for (int nt = 0; nt < 6; ++nt) {
        int col = wc0 + (nt << 4) + fm;
        float z = (acc[mt][nt][r] - mu) * rr * scv[nt] + biv[nt];
        float sw = z / (1.0f + __expf(-z));
        float t = sw + bf2f(x2[rg + col]);
        float ax = fabsf(t);
        outp[rg + col] =
            ax + __logf(1.0f + __expf(-2.0f * ax)) - 0.69314718055994531f;
      }
    }
#undef FSTG
#undef FCOMP
}

extern "C" void kernel_launch(void* const* d_in, const int* in_sizes, int n_in,
                              void* d_out, int out_size, void* d_ws, size_t ws_size,
                              hipStream_t stream) {
  const float* x = (const float*)d_in[0];
  const float* ln1_s = (const float*)d_in[1];
  const float* ln1_b = (const float*)d_in[2];
  const float* Wv = (const float*)d_in[3];
  const float* alpha = (const float*)d_in[4];
  const float* Wf = (const float*)d_in[5];
  const float* bf = (const float*)d_in[6];
  const float* lnf_s = (const float*)d_in[7];
  const float* lnf_b = (const float*)d_in[8];
  float* out = (float*)d_out;

  char* ws = (char*)d_ws;
  unsigned short* slotA = (unsigned short*)ws;
  unsigned short* Vt = (unsigned short*)(ws + 25165824);
  unsigned short* slotX = (unsigned short*)(ws + 50331648);
  unsigned short* W2t = (unsigned short*)(ws + 75497472);
  unsigned short* Wft = (unsigned short*)(ws + 76677120);

  hipFuncSetAttribute((const void*)gemm1_256,
                      hipFuncAttributeMaxDynamicSharedMemorySize, 131072);
  hipFuncSetAttribute((const void*)circ256_kernel,
                      hipFuncAttributeMaxDynamicSharedMemorySize, 86144);
  hipFuncSetAttribute((const void*)gemmf_ln0,
                      hipFuncAttributeMaxDynamicSharedMemorySize, 106496);
  hipFuncSetAttribute((const void*)gemmf_ln1,
                      hipFuncAttributeMaxDynamicSharedMemorySize, 106496);

  pack_all<<<6912, 256, 0, stream>>>(Wv, Wf, W2t, Wft);

  ln1_kernel<<<4096, 256, 0, stream>>>(x, ln1_s, ln1_b, slotA);
  gemm1_256<<<192, 512, 131072, stream>>>(slotA, W2t, Vt);
  circ256_kernel<<<192, 512, 86144, stream>>>(alpha, Vt, x, slotX);
  // FFN layer 0 fused: z1 = swish(LN(x2 @ Wf0 + bf0)) -> slotA (bf16)
  gemmf_ln0<<<256, 512, 106496, stream>>>(slotX, Wft, bf, lnf_s, lnf_b,
                                          slotA);
  // FFN layer 1 fused: out = log_cosh(swish(LN(z1 @ Wf1 + bf1)) + x2)
  gemmf_ln1<<<256, 512, 106496, stream>>>(slotA, Wft + 589824, bf + 768,
                                          lnf_s + 768, lnf_b + 768, slotX,
                                          out);
}

// Round 9
// 279.568 us; speedup vs baseline: 1.0149x; 1.0149x over previous
//
#include <hip/hip_runtime.h>
#include <cstdint>
#include <cstddef>

// B=16, N=1024, D=768, H=12, HS=64, L=2
// R15 changes vs R14 (283.7, passed):
//  - gemmf_ln0/ln1: 2-buffer depth-1 (WAITB(0)/step, latency-exposed:
//    2.5us/step vs 0.2us DMA floor) -> 3-buffer depth-2 counted vmcnt(7).
//    Each stage = 7 g2l16/thread; at each wait exactly the newest stage's
//    7 loads remain in flight => landing stage's latency hidden under one
//    full compute+issue step. LDS 104KB -> 156KB (3 x 26624 shorts), still
//    1 block/CU. Tail peeled: vmcnt(7) then vmcnt(0).
//  - Everything else byte-identical to R14.
//
// ws layout (bytes): unchanged.
//  [0, 25165824)          slotA : xn_bf16 -> z1_bf16
//  [25165824, 50331648)   Vt    : gemm1 out
//  [50331648, 75497472)   slotX : x2_bf16 (circ out)
//  [75497472, 76677120)   W2t
//  [76677120, 79036416)   Wft

typedef __attribute__((ext_vector_type(8))) short bf16x8;
typedef __attribute__((ext_vector_type(4))) float f32x4;
typedef __attribute__((ext_vector_type(4))) unsigned short us4;

__device__ __forceinline__ unsigned short f2bf(float f) {
  unsigned int u = __builtin_bit_cast(unsigned int, f);
  u += 0x7FFFu + ((u >> 16) & 1u);
  return (unsigned short)(u >> 16);
}
__device__ __forceinline__ float bf2f(unsigned short u) {
  return __builtin_bit_cast(float, (unsigned int)u << 16);
}

__device__ __forceinline__ void g2l16(const void* g, void* l) {
  __builtin_amdgcn_global_load_lds(
      (const __attribute__((address_space(1))) unsigned int*)g,
      (__attribute__((address_space(3))) unsigned int*)l,
      16, 0, 0);
}

#define WAITB(n) asm volatile("s_waitcnt vmcnt(" #n ") lgkmcnt(0)\n\ts_barrier" ::: "memory")
#define BARX asm volatile("s_waitcnt lgkmcnt(0)\n\ts_barrier" ::: "memory")
#define BARV(n) asm volatile("s_waitcnt vmcnt(" #n ") lgkmcnt(0)\n\ts_barrier" ::: "memory")

// ---------------- pack kernel (merged) ----------------
__global__ __launch_bounds__(256) void pack_all(const float* __restrict__ Wv,
                                                const float* __restrict__ Wf,
                                                unsigned short* __restrict__ W2t,
                                                unsigned short* __restrict__ Wft) {
  int bid = blockIdx.x;
  if (bid < 2304) {
    int o = bid * 256 + threadIdx.x;
    int np = o / 768, d = o - np * 768;
    int h = np >> 6, k = np & 63;
    W2t[o] = f2bf(Wv[h * 49152 + d * 64 + k]);
  } else {
    int o = (bid - 2304) * 256 + threadIdx.x;
    int l = o / 589824, rem = o - l * 589824;
    int np = rem / 768, d = rem - np * 768;
    Wft[o] = f2bf(Wf[l * 589824 + d * 768 + np]);
  }
}

// ---------------- row kernels ----------------
__device__ __forceinline__ void wave_reduce2(float& s, float& s2) {
#pragma unroll
  for (int off = 32; off > 0; off >>= 1) {
    s += __shfl_down(s, off);
    s2 += __shfl_down(s2, off);
  }
  s = __shfl(s, 0);
  s2 = __shfl(s2, 0);
}

__global__ __launch_bounds__(256) void ln1_kernel(const float* __restrict__ x,
                                                  const float* __restrict__ sc,
                                                  const float* __restrict__ bi,
                                                  unsigned short* __restrict__ out) {
  int row = blockIdx.x * 4 + (threadIdx.x >> 6);
  int lane = threadIdx.x & 63;
  size_t base = (size_t)row * 768;
  float4 v[3];
#pragma unroll
  for (int j = 0; j < 3; ++j) v[j] = *(const float4*)(x + base + lane * 4 + j * 256);
  float s = 0.f, s2 = 0.f;
#pragma unroll
  for (int j = 0; j < 3; ++j) {
    s += v[j].x + v[j].y + v[j].z + v[j].w;
    s2 += v[j].x * v[j].x + v[j].y * v[j].y + v[j].z * v[j].z + v[j].w * v[j].w;
  }
  wave_reduce2(s, s2);
  float mu = s * (1.0f / 768.0f);
  float var = s2 * (1.0f / 768.0f) - mu * mu;
  float r = rsqrtf(var + 1e-6f);
#pragma unroll
  for (int j = 0; j < 3; ++j) {
    int d = lane * 4 + j * 256;
    float4 scv = *(const float4*)(sc + d);
    float4 biv = *(const float4*)(bi + d);
    us4 o;
    o[0] = f2bf((v[j].x - mu) * r * scv.x + biv.x);
    o[1] = f2bf((v[j].y - mu) * r * scv.y + biv.y);
    o[2] = f2bf((v[j].z - mu) * r * scv.z + biv.z);
    o[3] = f2bf((v[j].w - mu) * r * scv.w + biv.w);
    *(us4*)(out + base + d) = o;
  }
}

// ---------- 256x256 8-phase dense GEMM core (R8 verbatim) ----------
template <int K>
__device__ __forceinline__ void gemm256(const unsigned short* __restrict__ A,
                                        const unsigned short* __restrict__ Bt,
                                        int m0, int n0, unsigned short* lds,
                                        f32x4 acc[8][4]) {
  const int tid = threadIdx.x;
  const int lane = tid & 63;
  const int wid = tid >> 6;
  const int wm = (wid >> 2) << 6;
  const int wn = (wid & 3) << 5;
  const int fm = lane & 15, fq = lane >> 4;
  const int srow = tid >> 3;
  const int sslot = (tid & 7) ^ (srow & 7);
  const size_t abase = (size_t)(m0 + srow) * K + (sslot << 3);
  const size_t bbase = (size_t)(n0 + srow) * K + (sslot << 3);

  bf16x8 aq[4][2], bq[4][2];

#define STG_A(kt, bb, c)                                                     \
  g2l16(A + abase + (size_t)((c) << 6) * K + ((kt) << 6),                    \
        lds + ((bb) << 15) + ((c) << 12) + (tid << 3))
#define STG_B(kt, bb, c)                                                     \
  g2l16(Bt + bbase + (size_t)((c) << 6) * K + ((kt) << 6),                   \
        lds + ((bb) << 15) + 16384 + ((c) << 12) + (tid << 3))
#define LDA(bb, mh)                                                          \
  _Pragma("unroll") for (int mt = 0; mt < 4; ++mt) {                         \
    const unsigned short* p =                                                \
        lds + ((bb) << 15) + (wm + ((mh) << 7) + (mt << 4) + fm) * 64;       \
    _Pragma("unroll") for (int kk = 0; kk < 2; ++kk)                         \
      aq[mt][kk] = *(const bf16x8*)(p + ((((kk << 2) + fq) ^ (fm & 7)) << 3)); \
  }
#define LDB(bb, nh)                                                          \
  _Pragma("unroll") for (int nt = 0; nt < 2; ++nt) {                         \
    const unsigned short* p = lds + ((bb) << 15) + 16384 +                   \
                              (wn + ((nh) << 7) + (nt << 4) + fm) * 64;      \
    _Pragma("unroll") for (int kk = 0; kk < 2; ++kk)                         \
      bq[((nh) << 1) + nt][kk] =                                             \
          *(const bf16x8*)(p + ((((kk << 2) + fq) ^ (fm & 7)) << 3));        \
  }
#define MMX(mh, nh)                                                          \
  {                                                                          \
    __builtin_amdgcn_s_setprio(1);                                           \
    _Pragma("unroll") for (int mt = 0; mt < 4; ++mt)                         \
    _Pragma("unroll") for (int nt = 0; nt < 2; ++nt)                         \
    _Pragma("unroll") for (int kk = 0; kk < 2; ++kk)                         \
      acc[((mh) << 2) + mt][((nh) << 1) + nt] =                              \
          __builtin_amdgcn_mfma_f32_16x16x32_bf16(                           \
              aq[mt][kk], bq[((nh) << 1) + nt][kk],                          \
              acc[((mh) << 2) + mt][((nh) << 1) + nt], 0, 0, 0);             \
    __builtin_amdgcn_s_setprio(0);                                           \
  }

  constexpr int NT = K >> 6;
  STG_A(0, 0, 0); STG_A(0, 0, 1); STG_A(0, 0, 2); STG_A(0, 0, 3);
  STG_B(0, 0, 0); STG_B(0, 0, 1); STG_B(0, 0, 2); STG_B(0, 0, 3);
  STG_A(1, 1, 0); STG_A(1, 1, 1);
  STG_B(1, 1, 0); STG_B(1, 1, 1);
  BARV(4);

  for (int t = 0; t < (NT >> 1) - 1; ++t) {
    const int k1 = 2 * t + 1, k2 = 2 * t + 2, k3 = 2 * t + 3;
    LDA(0, 0); LDB(0, 0);
    STG_A(k1, 1, 2); STG_A(k1, 1, 3);
    MMX(0, 0); BARX;
    LDB(0, 1);
    STG_B(k1, 1, 2); STG_B(k1, 1, 3);
    MMX(0, 1); BARX;
    LDA(0, 1);
    STG_A(k2, 0, 0); STG_A(k2, 0, 1);
    MMX(1, 0); BARX;
    STG_B(k2, 0, 0); STG_B(k2, 0, 1);
    MMX(1, 1); BARV(4);
    LDA(1, 0); LDB(1, 0);
    STG_A(k2, 0, 2); STG_A(k2, 0, 3);
    MMX(0, 0); BARX;
    LDB(1, 1);
    STG_B(k2, 0, 2); STG_B(k2, 0, 3);
    MMX(0, 1); BARX;
    LDA(1, 1);
    STG_A(k3, 1, 0); STG_A(k3, 1, 1);
    MMX(1, 0); BARX;
    STG_B(k3, 1, 0); STG_B(k3, 1, 1);
    MMX(1, 1); BARV(4);
  }
  {
    const int k1 = NT - 1;
    LDA(0, 0); LDB(0, 0);
    STG_A(k1, 1, 2); STG_A(k1, 1, 3);
    MMX(0, 0); BARX;
    LDB(0, 1);
    STG_B(k1, 1, 2); STG_B(k1, 1, 3);
    MMX(0, 1); BARX;
    LDA(0, 1);
    MMX(1, 0); BARX;
    MMX(1, 1);
    BARV(0);
    LDA(1, 0); LDB(1, 0);
    MMX(0, 0); BARX;
    LDB(1, 1);
    MMX(0, 1); BARX;
    LDA(1, 1);
    MMX(1, 0); BARX;
    MMX(1, 1);
  }
#undef STG_A
#undef STG_B
#undef LDA
#undef LDB
#undef MMX
}

__device__ __forceinline__ void decode256(int bid, int& m0, int& n0) {
  int wg = (bid & 7) * 24 + (bid >> 3);
  int mi = wg / 3, ni = wg - mi * 3;
  m0 = mi << 8;
  n0 = ni << 8;
}

// GEMM1: xn @ W2t -> Vt[h][b*64+k][n] (bf16)
__global__ __launch_bounds__(512, 2) void gemm1_256(const unsigned short* __restrict__ A,
                                                    const unsigned short* __restrict__ W2t,
                                                    unsigned short* __restrict__ Vt) {
  extern __shared__ unsigned short lds[];
  f32x4 acc[8][4] = {};
  int m0, n0;
  decode256(blockIdx.x, m0, n0);
  gemm256<768>(A, W2t, m0, n0, lds, acc);
  const int lane = threadIdx.x & 63, wid = threadIdx.x >> 6;
  const int wm = (wid >> 2) << 6, wn = (wid & 3) << 5;
  const int fm = lane & 15, fq = lane >> 4;
#pragma unroll
  for (int ai = 0; ai < 8; ++ai) {
    int rowb = m0 + wm + ((ai >> 2) << 7) + ((ai & 3) << 4) + (fq << 2);
    int b = rowb >> 10, n = rowb & 1023;
#pragma unroll
    for (int nj = 0; nj < 4; ++nj) {
      int col = n0 + wn + ((nj >> 1) << 7) + ((nj & 1) << 4) + fm;
      int h = col >> 6, ck = col & 63;
      size_t off = ((size_t)h << 20) + (size_t)((b << 6) + ck) * 1024 + n;
      us4 v;
#pragma unroll
      for (int r = 0; r < 4; ++r) v[r] = f2bf(acc[ai][nj][r]);
      *(us4*)(Vt + off) = v;
    }
  }
}

// ---------- circ 256x256 8-phase (R8 verbatim) ----------
__global__ __launch_bounds__(512, 2) void circ256_kernel(const float* __restrict__ alpha,
                                                         const unsigned short* __restrict__ Vt,
                                                         const float* __restrict__ xin,
                                                         unsigned short* __restrict__ x2bf) {
  extern __shared__ unsigned short lds[];
  unsigned short* sAc = lds;          // 8*1288 = 10304 shorts
  unsigned short* sB = lds + 10304;   // 2*16384 shorts
  f32x4 acc[8][4] = {};

  int wg = (blockIdx.x & 7) * 24 + (blockIdx.x >> 3);
  int h = wg >> 4, tt = wg & 15;
  int m0 = (tt >> 2) << 8, n0 = (tt & 3) << 8;

  const int tid = threadIdx.x;
  const int lane = tid & 63, wid = tid >> 6;
  const int wm = (wid >> 2) << 6, wn = (wid & 3) << 5;
  const int fm = lane & 15, fq = lane >> 4;
  const int srow = tid >> 3;
  const int sslot = (tid & 7) ^ (srow & 7);

  const float* ah = alpha + (h << 10);
#pragma unroll
  for (int c = 0; c < 8; ++c)
    for (int u = tid; u < 1280; u += 512)
      sAc[c * 1288 + u] = f2bf(ah[(m0 - 769 - u - c) & 1023]);

  const unsigned short* Bt = Vt + ((size_t)h << 20);
  const size_t bbase = (size_t)(n0 + srow) * 1024 + (sslot << 3);

  bf16x8 aq[4][2], bq[4][2];

#define CSTG(kt, bb, c)                                                      \
  g2l16(Bt + bbase + (size_t)((c) << 6) * 1024 + ((kt) << 6),                \
        sB + ((bb) << 14) + ((c) << 12) + (tid << 3))
#define CLDA(kt, mh)                                                         \
  _Pragma("unroll") for (int mt = 0; mt < 4; ++mt)                           \
  _Pragma("unroll") for (int kk = 0; kk < 2; ++kk) {                         \
    int d_ = ((kt) << 6) + (kk << 5) + (fq << 3) + 255 -                     \
             (wm + ((mh) << 7) + (mt << 4) + fm);                            \
    int c_ = d_ & 7;                                                         \
    aq[mt][kk] = *(const bf16x8*)(sAc + c_ * 1288 + (d_ - c_));              \
  }
#define CLDB(bb, nh)                                                         \
  _Pragma("unroll") for (int nt = 0; nt < 2; ++nt) {                         \
    const unsigned short* p =                                                \
        sB + ((bb) << 14) + (wn + ((nh) << 7) + (nt << 4) + fm) * 64;        \
    _Pragma("unroll") for (int kk = 0; kk < 2; ++kk)                         \
      bq[((nh) << 1) + nt][kk] =                                             \
          *(const bf16x8*)(p + ((((kk << 2) + fq) ^ (fm & 7)) << 3));        \
  }
#define CMMX(mh, nh)                                                         \
  {                                                                          \
    __builtin_amdgcn_s_setprio(1);                                           \
    _Pragma("unroll") for (int mt = 0; mt < 4; ++mt)                         \
    _Pragma("unroll") for (int nt = 0; nt < 2; ++nt)                         \
    _Pragma("unroll") for (int kk = 0; kk < 2; ++kk)                         \
      acc[((mh) << 2) + mt][((nh) << 1) + nt] =                              \
          __builtin_amdgcn_mfma_f32_16x16x32_bf16(                           \
              aq[mt][kk], bq[((nh) << 1) + nt][kk],                          \
              acc[((mh) << 2) + mt][((nh) << 1) + nt], 0, 0, 0);             \
    __builtin_amdgcn_s_setprio(0);                                           \
  }

  CSTG(0, 0, 0); CSTG(0, 0, 1); CSTG(0, 0, 2); CSTG(0, 0, 3);
  CSTG(1, 1, 0); CSTG(1, 1, 1);
  BARV(2);

  for (int it = 0; it < 7; ++it) {
    const int k0 = 2 * it, k1 = 2 * it + 1, k2 = 2 * it + 2, k3 = 2 * it + 3;
    CLDA(k0, 0); CLDB(0, 0);
    CSTG(k1, 1, 2);
    CMMX(0, 0); BARX;
    CLDB(0, 1);
    CSTG(k1, 1, 3);
    CMMX(0, 1); BARX;
    CLDA(k0, 1);
    CSTG(k2, 0, 0);
    CMMX(1, 0); BARX;
    CSTG(k2, 0, 1);
    CMMX(1, 1); BARV(2);
    CLDA(k1, 0); CLDB(1, 0);
    CSTG(k2, 0, 2);
    CMMX(0, 0); BARX;
    CLDB(1, 1);
    CSTG(k2, 0, 3);
    CMMX(0, 1); BARX;
    CLDA(k1, 1);
    CSTG(k3, 1, 0);
    CMMX(1, 0); BARX;
    CSTG(k3, 1, 1);
    CMMX(1, 1); BARV(2);
  }
  CLDA(14, 0); CLDB(0, 0);
  CSTG(15, 1, 2);
  CMMX(0, 0); BARX;
  CLDB(0, 1);
  CSTG(15, 1, 3);
  CMMX(0, 1); BARX;
  CLDA(14, 1);
  CMMX(1, 0); BARX;
  CMMX(1, 1);
  BARV(0);
  CLDA(15, 0); CLDB(1, 0);
  CMMX(0, 0); BARX;
  CLDB(1, 1);
  CMMX(0, 1); BARX;
  CLDA(15, 1);
  CMMX(1, 0); BARX;
  CMMX(1, 1);
#undef CSTG
#undef CLDA
#undef CLDB
#undef CMMX

#pragma unroll
  for (int ai = 0; ai < 8; ++ai) {
    int i = m0 + wm + ((ai >> 2) << 7) + ((ai & 3) << 4) + (fq << 2);
#pragma unroll
    for (int nj = 0; nj < 4; ++nj) {
      int col = n0 + wn + ((nj >> 1) << 7) + ((nj & 1) << 4) + fm;
      int b = col >> 6, k = col & 63;
      size_t off = ((size_t)(b << 10) + i) * 768 + (h << 6) + k;
#pragma unroll
      for (int r = 0; r < 4; ++r) {
        float val = acc[ai][nj][r] + xin[off + (size_t)r * 768];
        x2bf[off + (size_t)r * 768] = f2bf(val);
      }
    }
  }
}

// ---------- fused FFN layer-0: GEMM + bias + LN + swish -> z1 bf16 ----------
// R15: 3-buffer depth-2, counted vmcnt(7). Buffer b at lds + b*26624
// (sA 2048 + sB 24576 shorts per buffer). 156KB LDS, 1 block/CU, grid 256.
__global__ __launch_bounds__(512, 2) void gemmf_ln0(
    const unsigned short* __restrict__ A,
    const unsigned short* __restrict__ Wt,
    const float* __restrict__ bias,
    const float* __restrict__ sc,
    const float* __restrict__ bi,
    unsigned short* __restrict__ outp) {
  extern __shared__ unsigned short lds[];
  float* fst = (float*)lds;          // stats overlay (4.6KB) after drain

  f32x4 acc[4][6] = {};
  int bid = blockIdx.x;
  int p = ((bid & 7) << 5) + (bid >> 3);   // bijective XCD swizzle
  const int m0 = p << 6;

  const int tid = threadIdx.x;
  const int lane = tid & 63;
  const int wid = tid >> 6;
  const int fm = lane & 15, fq = lane >> 4;
  const int wc0 = wid * 96;
  const int brow = tid >> 2;
  const int cg = tid & 3;
  const size_t wbase = (size_t)brow * 768 + ((cg ^ ((brow >> 1) & 3)) << 3);
  const int t2 = tid & 255;
  const int ar = t2 >> 2;
  const size_t abase = (size_t)(m0 + ar) * 768 + ((cg ^ ((ar >> 1) & 3)) << 3);

#define FSTG(step, buf)                                                      \
  {                                                                          \
    int k0_ = (step) << 5;                                                   \
    unsigned short* base_ = lds + (buf) * 26624;                             \
    _Pragma("unroll") for (int c = 0; c < 6; ++c)                            \
      g2l16(Wt + wbase + c * 98304 + k0_,                                    \
            base_ + 2048 + c * 4096 + (tid << 3));                           \
    g2l16(A + abase + k0_, base_ + (t2 << 3));                               \
  }
#define FCOMP(buf)                                                           \
  {                                                                          \
    const unsigned short* base_ = lds + (buf) * 26624;                       \
    bf16x8 aq[4], bq[6];                                                     \
    _Pragma("unroll") for (int mt = 0; mt < 4; ++mt) {                       \
      int ra = (mt << 4) + fm;                                               \
      aq[mt] = *(const bf16x8*)(base_ + (ra << 5) +                          \
                                ((fq ^ ((ra >> 1) & 3)) << 3));              \
    }                                                                        \
    _Pragma("unroll") for (int nt = 0; nt < 6; ++nt) {                       \
      int rb = wc0 + (nt << 4) + fm;                                         \
      bq[nt] = *(const bf16x8*)(base_ + 2048 + (rb << 5) +                   \
                                ((fq ^ ((rb >> 1) & 3)) << 3));              \
    }                                                                        \
    __builtin_amdgcn_s_setprio(1);                                           \
    _Pragma("unroll") for (int mt = 0; mt < 4; ++mt)                         \
    _Pragma("unroll") for (int nt = 0; nt < 6; ++nt)                         \
      acc[mt][nt] = __builtin_amdgcn_mfma_f32_16x16x32_bf16(                 \
          aq[mt], bq[nt], acc[mt][nt], 0, 0, 0);                             \
    __builtin_amdgcn_s_setprio(0);                                           \
  }

  // depth-2 pipeline: 24 K-steps, 3 buffers.
  FSTG(0, 0);
  FSTG(1, 1);
  int bs = 2, bc = 0;
  for (int it = 0; it < 22; ++it) {
    WAITB(7);                 // stage(it) landed; stage(it+1)'s 7 in flight
    FSTG(it + 2, bs);
    bs = (bs == 2) ? 0 : bs + 1;
    FCOMP(bc);
    bc = (bc == 2) ? 0 : bc + 1;
  }
  WAITB(7);                   // stage(22) landed; stage(23) in flight
  FCOMP(bc);
  bc = (bc == 2) ? 0 : bc + 1;
  WAITB(0);                   // stage(23) landed
  FCOMP(bc);
  __syncthreads();            // full drain before stats overlay

  float bcv[6];
#pragma unroll
  for (int nt = 0; nt < 6; ++nt) bcv[nt] = bias[wc0 + (nt << 4) + fm];
#pragma unroll
  for (int mt = 0; mt < 4; ++mt)
#pragma unroll
    for (int nt = 0; nt < 6; ++nt)
#pragma unroll
      for (int r = 0; r < 4; ++r) acc[mt][nt][r] += bcv[nt];

  float s[4][4], s2[4][4];
#pragma unroll
  for (int mt = 0; mt < 4; ++mt)
#pragma unroll
    for (int r = 0; r < 4; ++r) {
      float a = 0.f, b2 = 0.f;
#pragma unroll
      for (int nt = 0; nt < 6; ++nt) {
        float v = acc[mt][nt][r];
        a += v;
        b2 += v * v;
      }
      s[mt][r] = a;
      s2[mt][r] = b2;
    }
#pragma unroll
  for (int off = 1; off <= 8; off <<= 1)
#pragma unroll
    for (int mt = 0; mt < 4; ++mt)
#pragma unroll
      for (int r = 0; r < 4; ++r) {
        s[mt][r] += __shfl_xor(s[mt][r], off);
        s2[mt][r] += __shfl_xor(s2[mt][r], off);
      }
  if (fm == 0) {
#pragma unroll
    for (int mt = 0; mt < 4; ++mt)
#pragma unroll
      for (int r = 0; r < 4; ++r) {
        int row = (mt << 4) + (fq << 2) + r;
        fst[wid * 64 + row] = s[mt][r];
        fst[512 + wid * 64 + row] = s2[mt][r];
      }
  }
  __syncthreads();
  if (tid < 64) {
    float ts = 0.f, ts2 = 0.f;
#pragma unroll
    for (int w = 0; w < 8; ++w) {
      ts += fst[w * 64 + tid];
      ts2 += fst[512 + w * 64 + tid];
    }
    float mu = ts * (1.0f / 768.0f);
    float var = ts2 * (1.0f / 768.0f) - mu * mu;
    fst[1024 + tid] = mu;
    fst[1088 + tid] = rsqrtf(var + 1e-6f);
  }
  __syncthreads();

  float scv[6], biv[6];
#pragma unroll
  for (int nt = 0; nt < 6; ++nt) {
    scv[nt] = sc[wc0 + (nt << 4) + fm];
    biv[nt] = bi[wc0 + (nt << 4) + fm];
  }
#pragma unroll
  for (int mt = 0; mt < 4; ++mt)
#pragma unroll
    for (int r = 0; r < 4; ++r) {
      int row = (mt << 4) + (fq << 2) + r;
      float mu = fst[1024 + row];
      float rr = fst[1088 + row];
      size_t rg = (size_t)(m0 + row) * 768;
#pragma unroll
      for (int nt = 0; nt < 6; ++nt) {
        int col = wc0 + (nt << 4) + fm;
        float z = (acc[mt][nt][r] - mu) * rr * scv[nt] + biv[nt];
        outp[rg + col] = f2bf(z / (1.0f + __expf(-z)));
      }
    }
#undef FSTG
#undef FCOMP
}

// ---------- fused FFN layer-1: GEMM + bias + LN + swish + residual +
// log_cosh -> f32 out. R15: same 3-buffer depth-2 loop as gemmf_ln0. ------
__global__ __launch_bounds__(512, 2) void gemmf_ln1(
    const unsigned short* __restrict__ A,
    const unsigned short* __restrict__ Wt,
    const float* __restrict__ bias,
    const float* __restrict__ sc,
    const float* __restrict__ bi,
    const unsigned short* __restrict__ x2,
    float* __restrict__ outp) {
  extern __shared__ unsigned short lds[];
  float* fst = (float*)lds;

  f32x4 acc[4][6] = {};
  int bid = blockIdx.x;
  int p = ((bid & 7) << 5) + (bid >> 3);
  const int m0 = p << 6;

  const int tid = threadIdx.x;
  const int lane = tid & 63;
  const int wid = tid >> 6;
  const int fm = lane & 15, fq = lane >> 4;
  const int wc0 = wid * 96;
  const int brow = tid >> 2;
  const int cg = tid & 3;
  const size_t wbase = (size_t)brow * 768 + ((cg ^ ((brow >> 1) & 3)) << 3);
  const int t2 = tid & 255;
  const int ar = t2 >> 2;
  const size_t abase = (size_t)(m0 + ar) * 768 + ((cg ^ ((ar >> 1) & 3)) << 3);

#define FSTG(step, buf)                                                      \
  {                                                                          \
    int k0_ = (step) << 5;                                                   \
    unsigned short* base_ = lds + (buf) * 26624;                             \
    _Pragma("unroll") for (int c = 0; c < 6; ++c)                            \
      g2l16(Wt + wbase + c * 98304 + k0_,                                    \
            base_ + 2048 + c * 4096 + (tid << 3));                           \
    g2l16(A + abase + k0_, base_ + (t2 << 3));                               \
  }
#define FCOMP(buf)                                                           \
  {                                                                          \
    const unsigned short* base_ = lds + (buf) * 26624;                       \
    bf16x8 aq[4], bq[6];                                                     \
    _Pragma("unroll") for (int mt = 0; mt < 4; ++mt) {                       \
      int ra = (mt << 4) + fm;                                               \
      aq[mt] = *(const bf16x8*)(base_ + (ra << 5) +                          \
                                ((fq ^ ((ra >> 1) & 3)) << 3));              \
    }                                                                        \
    _Pragma("unroll") for (int nt = 0; nt < 6; ++nt) {                       \
      int rb = wc0 + (nt << 4) + fm;                                         \
      bq[nt] = *(const bf16x8*)(base_ + 2048 + (rb << 5) +                   \
                                ((fq ^ ((rb >> 1) & 3)) << 3));              \
    }                                                                        \
    __builtin_amdgcn_s_setprio(1);                                           \
    _Pragma("unroll") for (int mt = 0; mt < 4; ++mt)                         \
    _Pragma("unroll") for (int nt = 0; nt < 6; ++nt)                         \
      acc[mt][nt] = __builtin_amdgcn_mfma_f32_16x16x32_bf16(                 \
          aq[mt], bq[nt], acc[mt][nt], 0, 0, 0);                             \
    __builtin_amdgcn_s_setprio(0);                                           \
  }

  FSTG(0, 0);
  FSTG(1, 1);
  int bs = 2, bc = 0;
  for (int it = 0; it < 22; ++it) {
    WAITB(7);
    FSTG(it + 2, bs);
    bs = (bs == 2) ? 0 : bs + 1;
    FCOMP(bc);
    bc = (bc == 2) ? 0 : bc + 1;
  }
  WAITB(7);
  FCOMP(bc);
  bc = (bc == 2) ? 0 : bc + 1;
  WAITB(0);
  FCOMP(bc);
  __syncthreads();

  float bcv[6];
#pragma unroll
  for (int nt = 0; nt < 6; ++nt) bcv[nt] = bias[wc0 + (nt << 4) + fm];
#pragma unroll
  for (int mt = 0; mt < 4; ++mt)
#pragma unroll
    for (int nt = 0; nt < 6; ++nt)
#pragma unroll
      for (int r = 0; r < 4; ++r) acc[mt][nt][r] += bcv[nt];

  float s[4][4], s2[4][4];
#pragma unroll
  for (int mt = 0; mt < 4; ++mt)
#pragma unroll
    for (int r = 0; r < 4; ++r) {
      float a = 0.f, b2 = 0.f;
#pragma unroll
      for (int nt = 0; nt < 6; ++nt) {
        float v = acc[mt][nt][r];
        a += v;
        b2 += v * v;
      }
      s[mt][r] = a;
      s2[mt][r] = b2;
    }
#pragma unroll
  for (int off = 1; off <= 8; off <<= 1)
#pragma unroll
    for (int mt = 0; mt < 4; ++mt)
#pragma unroll
      for (int r = 0; r < 4; ++r) {
        s[mt][r] += __shfl_xor(s[mt][r], off);
        s2[mt][r] += __shfl_xor(s2[mt][r], off);
      }
  if (fm == 0) {
#pragma unroll
    for (int mt = 0; mt < 4; ++mt)
#pragma unroll
      for (int r = 0; r < 4; ++r) {
        int row = (mt << 4) + (fq << 2) + r;
        fst[wid * 64 + row] = s[mt][r];
        fst[512 + wid * 64 + row] = s2[mt][r];
      }
  }
  __syncthreads();
  if (tid < 64) {
    float ts = 0.f, ts2 = 0.f;
#pragma unroll
    for (int w = 0; w < 8; ++w) {
      ts += fst[w * 64 + tid];
      ts2 += fst[512 + w * 64 + tid];
    }
    float mu = ts * (1.0f / 768.0f);
    float var = ts2 * (1.0f / 768.0f) - mu * mu;
    fst[1024 + tid] = mu;
    fst[1088 + tid] = rsqrtf(var + 1e-6f);
  }
  __syncthreads();

  float scv[6], biv[6];
#pragma unroll
  for (int nt = 0; nt < 6; ++nt) {
    scv[nt] = sc[wc0 + (nt << 4) + fm];
    biv[nt] = bi[wc0 + (nt << 4) + fm];
  }
#pragma unroll
  for (int mt = 0; mt < 4; ++mt)
#pragma unroll
    for (int r = 0; r < 4; ++r) {
      int row = (mt << 4) + (fq << 2) + r;
      float mu = fst[1024 + row];
      float rr = fst[1088 + row];
      size_t rg = (size_t)(m0 + row) * 768;
#pragma unroll
      for (int nt = 0; nt < 6; ++nt) {
        int col = wc0 + (nt << 4) + fm;
        float z = (acc[mt][nt][r] - mu) * rr * scv[nt] + biv[nt];
        float sw = z / (1.0f + __expf(-z));
        float t = sw + bf2f(x2[rg + col]);
        float ax = fabsf(t);
        outp[rg + col] =
            ax + __logf(1.0f + __expf(-2.0f * ax)) - 0.69314718055994531f;
      }
    }
#undef FSTG
#undef FCOMP
}

extern "C" void kernel_launch(void* const* d_in, const int* in_sizes, int n_in,
                              void* d_out, int out_size, void* d_ws, size_t ws_size,
                              hipStream_t stream) {
  const float* x = (const float*)d_in[0];
  const float* ln1_s = (const float*)d_in[1];
  const float* ln1_b = (const float*)d_in[2];
  const float* Wv = (const float*)d_in[3];
  const float* alpha = (const float*)d_in[4];
  const float* Wf = (const float*)d_in[5];
  const float* bf = (const float*)d_in[6];
  const float* lnf_s = (const float*)d_in[7];
  const float* lnf_b = (const float*)d_in[8];
  float* out = (float*)d_out;

  char* ws = (char*)d_ws;
  unsigned short* slotA = (unsigned short*)ws;
  unsigned short* Vt = (unsigned short*)(ws + 25165824);
  unsigned short* slotX = (unsigned short*)(ws + 50331648);
  unsigned short* W2t = (unsigned short*)(ws + 75497472);
  unsigned short* Wft = (unsigned short*)(ws + 76677120);

  hipFuncSetAttribute((const void*)gemm1_256,
                      hipFuncAttributeMaxDynamicSharedMemorySize, 131072);
  hipFuncSetAttribute((const void*)circ256_kernel,
                      hipFuncAttributeMaxDynamicSharedMemorySize, 86144);
  hipFuncSetAttribute((const void*)gemmf_ln0,
                      hipFuncAttributeMaxDynamicSharedMemorySize, 159744);
  hipFuncSetAttribute((const void*)gemmf_ln1,
                      hipFuncAttributeMaxDynamicSharedMemorySize, 159744);

  pack_all<<<6912, 256, 0, stream>>>(Wv, Wf, W2t, Wft);

  ln1_kernel<<<4096, 256, 0, stream>>>(x, ln1_s, ln1_b, slotA);
  gemm1_256<<<192, 512, 131072, stream>>>(slotA, W2t, Vt);
  circ256_kernel<<<192, 512, 86144, stream>>>(alpha, Vt, x, slotX);
  // FFN layer 0 fused: z1 = swish(LN(x2 @ Wf0 + bf0)) -> slotA (bf16)
  gemmf_ln0<<<256, 512, 159744, stream>>>(slotX, Wft, bf, lnf_s, lnf_b,
                                          slotA);
  // FFN layer 1 fused: out = log_cosh(swish(LN(z1 @ Wf1 + bf1)) + x2)
  gemmf_ln1<<<256, 512, 159744, stream>>>(slotA, Wft + 589824, bf + 768,
                                          lnf_s + 768, lnf_b + 768, slotX,
                                          out);
}

// Round 10
// 267.798 us; speedup vs baseline: 1.0595x; 1.0439x over previous
//
#include <hip/hip_runtime.h>
#include <cstdint>
#include <cstddef>

// B=16, N=1024, D=768, H=12, HS=64, L=2
// R16 = R8 exact (best measured 270.3) + pack_all merged into ln1
// ("prelude_kernel", blockIdx split; pack and ln1 are independent).
// Fused-FFN family (R13-R15) measured net-negative -> dropped.
// Dispatches 8 -> 7 (~6us/launch gap measured from timeline gaps).
//
// ws layout (bytes): unchanged.
//  [0, 25165824)          slotA : xn_bf16 -> z1_bf16
//  [25165824, 50331648)   Vt    : gemm1 out ; reused as gbf
//  [50331648, 75497472)   slotX : x2_bf16 (circ out)
//  [75497472, 76677120)   W2t
//  [76677120, 79036416)   Wft

typedef __attribute__((ext_vector_type(8))) short bf16x8;
typedef __attribute__((ext_vector_type(4))) float f32x4;
typedef __attribute__((ext_vector_type(4))) unsigned short us4;

__device__ __forceinline__ unsigned short f2bf(float f) {
  unsigned int u = __builtin_bit_cast(unsigned int, f);
  u += 0x7FFFu + ((u >> 16) & 1u);
  return (unsigned short)(u >> 16);
}
__device__ __forceinline__ float bf2f(unsigned short u) {
  return __builtin_bit_cast(float, (unsigned int)u << 16);
}

__device__ __forceinline__ void g2l16(const void* g, void* l) {
  __builtin_amdgcn_global_load_lds(
      (const __attribute__((address_space(1))) unsigned int*)g,
      (__attribute__((address_space(3))) unsigned int*)l,
      16, 0, 0);
}

#define BARX asm volatile("s_waitcnt lgkmcnt(0)\n\ts_barrier" ::: "memory")
#define BARV(n) asm volatile("s_waitcnt vmcnt(" #n ") lgkmcnt(0)\n\ts_barrier" ::: "memory")

// ---------------- row-kernel helper ----------------
__device__ __forceinline__ void wave_reduce2(float& s, float& s2) {
#pragma unroll
  for (int off = 32; off > 0; off >>= 1) {
    s += __shfl_down(s, off);
    s2 += __shfl_down(s2, off);
  }
  s = __shfl(s, 0);
  s2 = __shfl(s2, 0);
}

// ---------------- prelude: weight pack (blocks 0..6911) + ln1 (6912..) ----
__global__ __launch_bounds__(256) void prelude_kernel(
    const float* __restrict__ Wv, const float* __restrict__ Wf,
    unsigned short* __restrict__ W2t, unsigned short* __restrict__ Wft,
    const float* __restrict__ x, const float* __restrict__ sc,
    const float* __restrict__ bi, unsigned short* __restrict__ xn) {
  int bid = blockIdx.x;
  if (bid < 2304) {
    int o = bid * 256 + threadIdx.x;
    int np = o / 768, d = o - np * 768;
    int h = np >> 6, k = np & 63;
    W2t[o] = f2bf(Wv[h * 49152 + d * 64 + k]);
    return;
  }
  if (bid < 6912) {
    int o = (bid - 2304) * 256 + threadIdx.x;
    int l = o / 589824, rem = o - l * 589824;
    int np = rem / 768, d = rem - np * 768;
    Wft[o] = f2bf(Wf[l * 589824 + d * 768 + np]);
    return;
  }
  // ln1: row kernel, 4 rows/block
  int row = (bid - 6912) * 4 + (threadIdx.x >> 6);
  int lane = threadIdx.x & 63;
  size_t base = (size_t)row * 768;
  float4 v[3];
#pragma unroll
  for (int j = 0; j < 3; ++j) v[j] = *(const float4*)(x + base + lane * 4 + j * 256);
  float s = 0.f, s2 = 0.f;
#pragma unroll
  for (int j = 0; j < 3; ++j) {
    s += v[j].x + v[j].y + v[j].z + v[j].w;
    s2 += v[j].x * v[j].x + v[j].y * v[j].y + v[j].z * v[j].z + v[j].w * v[j].w;
  }
  wave_reduce2(s, s2);
  float mu = s * (1.0f / 768.0f);
  float var = s2 * (1.0f / 768.0f) - mu * mu;
  float r = rsqrtf(var + 1e-6f);
#pragma unroll
  for (int j = 0; j < 3; ++j) {
    int d = lane * 4 + j * 256;
    float4 scv = *(const float4*)(sc + d);
    float4 biv = *(const float4*)(bi + d);
    us4 o;
    o[0] = f2bf((v[j].x - mu) * r * scv.x + biv.x);
    o[1] = f2bf((v[j].y - mu) * r * scv.y + biv.y);
    o[2] = f2bf((v[j].z - mu) * r * scv.z + biv.z);
    o[3] = f2bf((v[j].w - mu) * r * scv.w + biv.w);
    *(us4*)(xn + base + d) = o;
  }
}

__global__ __launch_bounds__(256) void lnswish_kernel(const unsigned short* __restrict__ g,
                                                      const float* __restrict__ sc,
                                                      const float* __restrict__ bi,
                                                      unsigned short* __restrict__ out) {
  int row = blockIdx.x * 4 + (threadIdx.x >> 6);
  int lane = threadIdx.x & 63;
  size_t base = (size_t)row * 768;
  float v[3][4];
#pragma unroll
  for (int j = 0; j < 3; ++j) {
    us4 gv = *(const us4*)(g + base + lane * 4 + j * 256);
#pragma unroll
    for (int q = 0; q < 4; ++q) v[j][q] = bf2f(gv[q]);
  }
  float s = 0.f, s2 = 0.f;
#pragma unroll
  for (int j = 0; j < 3; ++j)
#pragma unroll
    for (int q = 0; q < 4; ++q) { s += v[j][q]; s2 += v[j][q] * v[j][q]; }
  wave_reduce2(s, s2);
  float mu = s * (1.0f / 768.0f);
  float var = s2 * (1.0f / 768.0f) - mu * mu;
  float r = rsqrtf(var + 1e-6f);
#pragma unroll
  for (int j = 0; j < 3; ++j) {
    int d = lane * 4 + j * 256;
    float4 scv = *(const float4*)(sc + d);
    float4 biv = *(const float4*)(bi + d);
    const float* scp = &scv.x;
    const float* bip = &biv.x;
    us4 o;
#pragma unroll
    for (int q = 0; q < 4; ++q) {
      float z = (v[j][q] - mu) * r * scp[q] + bip[q];
      o[q] = f2bf(z / (1.0f + __expf(-z)));
    }
    *(us4*)(out + base + d) = o;
  }
}

__global__ __launch_bounds__(256) void final_kernel(const unsigned short* __restrict__ g,
                                                    const float* __restrict__ sc,
                                                    const float* __restrict__ bi,
                                                    const unsigned short* __restrict__ x2,
                                                    float* __restrict__ out) {
  int row = blockIdx.x * 4 + (threadIdx.x >> 6);
  int lane = threadIdx.x & 63;
  size_t base = (size_t)row * 768;
  float v[3][4];
#pragma unroll
  for (int j = 0; j < 3; ++j) {
    us4 gv = *(const us4*)(g + base + lane * 4 + j * 256);
#pragma unroll
    for (int q = 0; q < 4; ++q) v[j][q] = bf2f(gv[q]);
  }
  float s = 0.f, s2 = 0.f;
#pragma unroll
  for (int j = 0; j < 3; ++j)
#pragma unroll
    for (int q = 0; q < 4; ++q) { s += v[j][q]; s2 += v[j][q] * v[j][q]; }
  wave_reduce2(s, s2);
  float mu = s * (1.0f / 768.0f);
  float var = s2 * (1.0f / 768.0f) - mu * mu;
  float r = rsqrtf(var + 1e-6f);
#pragma unroll
  for (int j = 0; j < 3; ++j) {
    int d = lane * 4 + j * 256;
    float4 scv = *(const float4*)(sc + d);
    float4 biv = *(const float4*)(bi + d);
    us4 xv = *(const us4*)(x2 + base + d);
    const float* scp = &scv.x;
    const float* bip = &biv.x;
    float4 o;
    float* op = &o.x;
#pragma unroll
    for (int q = 0; q < 4; ++q) {
      float z = (v[j][q] - mu) * r * scp[q] + bip[q];
      float sw = z / (1.0f + __expf(-z));
      float t = sw + bf2f(xv[q]);
      float ax = fabsf(t);
      op[q] = ax + __logf(1.0f + __expf(-2.0f * ax)) - 0.69314718055994531f;
    }
    *(float4*)(out + base + d) = o;
  }
}

// ---------- 256x256 8-phase dense GEMM core (R8 verbatim) ----------
template <int K>
__device__ __forceinline__ void gemm256(const unsigned short* __restrict__ A,
                                        const unsigned short* __restrict__ Bt,
                                        int m0, int n0, unsigned short* lds,
                                        f32x4 acc[8][4]) {
  const int tid = threadIdx.x;
  const int lane = tid & 63;
  const int wid = tid >> 6;
  const int wm = (wid >> 2) << 6;
  const int wn = (wid & 3) << 5;
  const int fm = lane & 15, fq = lane >> 4;
  const int srow = tid >> 3;
  const int sslot = (tid & 7) ^ (srow & 7);
  const size_t abase = (size_t)(m0 + srow) * K + (sslot << 3);
  const size_t bbase = (size_t)(n0 + srow) * K + (sslot << 3);

  bf16x8 aq[4][2], bq[4][2];

#define STG_A(kt, bb, c)                                                     \
  g2l16(A + abase + (size_t)((c) << 6) * K + ((kt) << 6),                    \
        lds + ((bb) << 15) + ((c) << 12) + (tid << 3))
#define STG_B(kt, bb, c)                                                     \
  g2l16(Bt + bbase + (size_t)((c) << 6) * K + ((kt) << 6),                   \
        lds + ((bb) << 15) + 16384 + ((c) << 12) + (tid << 3))
#define LDA(bb, mh)                                                          \
  _Pragma("unroll") for (int mt = 0; mt < 4; ++mt) {                         \
    const unsigned short* p =                                                \
        lds + ((bb) << 15) + (wm + ((mh) << 7) + (mt << 4) + fm) * 64;       \
    _Pragma("unroll") for (int kk = 0; kk < 2; ++kk)                         \
      aq[mt][kk] = *(const bf16x8*)(p + ((((kk << 2) + fq) ^ (fm & 7)) << 3)); \
  }
#define LDB(bb, nh)                                                          \
  _Pragma("unroll") for (int nt = 0; nt < 2; ++nt) {                         \
    const unsigned short* p = lds + ((bb) << 15) + 16384 +                   \
                              (wn + ((nh) << 7) + (nt << 4) + fm) * 64;      \
    _Pragma("unroll") for (int kk = 0; kk < 2; ++kk)                         \
      bq[((nh) << 1) + nt][kk] =                                             \
          *(const bf16x8*)(p + ((((kk << 2) + fq) ^ (fm & 7)) << 3));        \
  }
#define MMX(mh, nh)                                                          \
  {                                                                          \
    __builtin_amdgcn_s_setprio(1);                                           \
    _Pragma("unroll") for (int mt = 0; mt < 4; ++mt)                         \
    _Pragma("unroll") for (int nt = 0; nt < 2; ++nt)                         \
    _Pragma("unroll") for (int kk = 0; kk < 2; ++kk)                         \
      acc[((mh) << 2) + mt][((nh) << 1) + nt] =                              \
          __builtin_amdgcn_mfma_f32_16x16x32_bf16(                           \
              aq[mt][kk], bq[((nh) << 1) + nt][kk],                          \
              acc[((mh) << 2) + mt][((nh) << 1) + nt], 0, 0, 0);             \
    __builtin_amdgcn_s_setprio(0);                                           \
  }

  constexpr int NT = K >> 6;
  STG_A(0, 0, 0); STG_A(0, 0, 1); STG_A(0, 0, 2); STG_A(0, 0, 3);
  STG_B(0, 0, 0); STG_B(0, 0, 1); STG_B(0, 0, 2); STG_B(0, 0, 3);
  STG_A(1, 1, 0); STG_A(1, 1, 1);
  STG_B(1, 1, 0); STG_B(1, 1, 1);
  BARV(4);

  for (int t = 0; t < (NT >> 1) - 1; ++t) {
    const int k1 = 2 * t + 1, k2 = 2 * t + 2, k3 = 2 * t + 3;
    LDA(0, 0); LDB(0, 0);
    STG_A(k1, 1, 2); STG_A(k1, 1, 3);
    MMX(0, 0); BARX;
    LDB(0, 1);
    STG_B(k1, 1, 2); STG_B(k1, 1, 3);
    MMX(0, 1); BARX;
    LDA(0, 1);
    STG_A(k2, 0, 0); STG_A(k2, 0, 1);
    MMX(1, 0); BARX;
    STG_B(k2, 0, 0); STG_B(k2, 0, 1);
    MMX(1, 1); BARV(4);
    LDA(1, 0); LDB(1, 0);
    STG_A(k2, 0, 2); STG_A(k2, 0, 3);
    MMX(0, 0); BARX;
    LDB(1, 1);
    STG_B(k2, 0, 2); STG_B(k2, 0, 3);
    MMX(0, 1); BARX;
    LDA(1, 1);
    STG_A(k3, 1, 0); STG_A(k3, 1, 1);
    MMX(1, 0); BARX;
    STG_B(k3, 1, 0); STG_B(k3, 1, 1);
    MMX(1, 1); BARV(4);
  }
  {
    const int k1 = NT - 1;
    LDA(0, 0); LDB(0, 0);
    STG_A(k1, 1, 2); STG_A(k1, 1, 3);
    MMX(0, 0); BARX;
    LDB(0, 1);
    STG_B(k1, 1, 2); STG_B(k1, 1, 3);
    MMX(0, 1); BARX;
    LDA(0, 1);
    MMX(1, 0); BARX;
    MMX(1, 1);
    BARV(0);
    LDA(1, 0); LDB(1, 0);
    MMX(0, 0); BARX;
    LDB(1, 1);
    MMX(0, 1); BARX;
    LDA(1, 1);
    MMX(1, 0); BARX;
    MMX(1, 1);
  }
#undef STG_A
#undef STG_B
#undef LDA
#undef LDB
#undef MMX
}

__device__ __forceinline__ void decode256(int bid, int& m0, int& n0) {
  int wg = (bid & 7) * 24 + (bid >> 3);
  int mi = wg / 3, ni = wg - mi * 3;
  m0 = mi << 8;
  n0 = ni << 8;
}

// GEMM1: xn @ W2t -> Vt[h][b*64+k][n] (bf16)
__global__ __launch_bounds__(512, 2) void gemm1_256(const unsigned short* __restrict__ A,
                                                    const unsigned short* __restrict__ W2t,
                                                    unsigned short* __restrict__ Vt) {
  extern __shared__ unsigned short lds[];
  f32x4 acc[8][4] = {};
  int m0, n0;
  decode256(blockIdx.x, m0, n0);
  gemm256<768>(A, W2t, m0, n0, lds, acc);
  const int lane = threadIdx.x & 63, wid = threadIdx.x >> 6;
  const int wm = (wid >> 2) << 6, wn = (wid & 3) << 5;
  const int fm = lane & 15, fq = lane >> 4;
#pragma unroll
  for (int ai = 0; ai < 8; ++ai) {
    int rowb = m0 + wm + ((ai >> 2) << 7) + ((ai & 3) << 4) + (fq << 2);
    int b = rowb >> 10, n = rowb & 1023;
#pragma unroll
    for (int nj = 0; nj < 4; ++nj) {
      int col = n0 + wn + ((nj >> 1) << 7) + ((nj & 1) << 4) + fm;
      int h = col >> 6, ck = col & 63;
      size_t off = ((size_t)h << 20) + (size_t)((b << 6) + ck) * 1024 + n;
      us4 v;
#pragma unroll
      for (int r = 0; r < 4; ++r) v[r] = f2bf(acc[ai][nj][r]);
      *(us4*)(Vt + off) = v;
    }
  }
}

// FFN GEMM: A(bf16) @ Wt + bias -> g (bf16)
__global__ __launch_bounds__(512, 2) void gemmf_256(const unsigned short* __restrict__ A,
                                                    const unsigned short* __restrict__ Bt,
                                                    const float* __restrict__ bias,
                                                    unsigned short* __restrict__ g) {
  extern __shared__ unsigned short lds[];
  f32x4 acc[8][4] = {};
  int m0, n0;
  decode256(blockIdx.x, m0, n0);
  gemm256<768>(A, Bt, m0, n0, lds, acc);
  const int lane = threadIdx.x & 63, wid = threadIdx.x >> 6;
  const int wm = (wid >> 2) << 6, wn = (wid & 3) << 5;
  const int fm = lane & 15, fq = lane >> 4;
#pragma unroll
  for (int ai = 0; ai < 8; ++ai) {
    int rowb = m0 + wm + ((ai >> 2) << 7) + ((ai & 3) << 4) + (fq << 2);
#pragma unroll
    for (int nj = 0; nj < 4; ++nj) {
      int col = n0 + wn + ((nj >> 1) << 7) + ((nj & 1) << 4) + fm;
      float bc = bias[col];
#pragma unroll
      for (int r = 0; r < 4; ++r)
        g[(size_t)(rowb + r) * 768 + col] = f2bf(acc[ai][nj][r] + bc);
    }
  }
}

// ---------- circ 256x256 8-phase (R8 verbatim) ----------
__global__ __launch_bounds__(512, 2) void circ256_kernel(const float* __restrict__ alpha,
                                                         const unsigned short* __restrict__ Vt,
                                                         const float* __restrict__ xin,
                                                         unsigned short* __restrict__ x2bf) {
  extern __shared__ unsigned short lds[];
  unsigned short* sAc = lds;          // 8*1288 = 10304 shorts
  unsigned short* sB = lds + 10304;   // 2*16384 shorts
  f32x4 acc[8][4] = {};

  int wg = (blockIdx.x & 7) * 24 + (blockIdx.x >> 3);
  int h = wg >> 4, tt = wg & 15;
  int m0 = (tt >> 2) << 8, n0 = (tt & 3) << 8;

  const int tid = threadIdx.x;
  const int lane = tid & 63, wid = tid >> 6;
  const int wm = (wid >> 2) << 6, wn = (wid & 3) << 5;
  const int fm = lane & 15, fq = lane >> 4;
  const int srow = tid >> 3;
  const int sslot = (tid & 7) ^ (srow & 7);

  const float* ah = alpha + (h << 10);
#pragma unroll
  for (int c = 0; c < 8; ++c)
    for (int u = tid; u < 1280; u += 512)
      sAc[c * 1288 + u] = f2bf(ah[(m0 - 769 - u - c) & 1023]);

  const unsigned short* Bt = Vt + ((size_t)h << 20);
  const size_t bbase = (size_t)(n0 + srow) * 1024 + (sslot << 3);

  bf16x8 aq[4][2], bq[4][2];

#define CSTG(kt, bb, c)                                                      \
  g2l16(Bt + bbase + (size_t)((c) << 6) * 1024 + ((kt) << 6),                \
        sB + ((bb) << 14) + ((c) << 12) + (tid << 3))
#define CLDA(kt, mh)                                                         \
  _Pragma("unroll") for (int mt = 0; mt < 4; ++mt)                           \
  _Pragma("unroll") for (int kk = 0; kk < 2; ++kk) {                         \
    int d_ = ((kt) << 6) + (kk << 5) + (fq << 3) + 255 -                     \
             (wm + ((mh) << 7) + (mt << 4) + fm);                            \
    int c_ = d_ & 7;                                                         \
    aq[mt][kk] = *(const bf16x8*)(sAc + c_ * 1288 + (d_ - c_));              \
  }
#define CLDB(bb, nh)                                                         \
  _Pragma("unroll") for (int nt = 0; nt < 2; ++nt) {                         \
    const unsigned short* p =                                                \
        sB + ((bb) << 14) + (wn + ((nh) << 7) + (nt << 4) + fm) * 64;        \
    _Pragma("unroll") for (int kk = 0; kk < 2; ++kk)                         \
      bq[((nh) << 1) + nt][kk] =                                             \
          *(const bf16x8*)(p + ((((kk << 2) + fq) ^ (fm & 7)) << 3));        \
  }
#define CMMX(mh, nh)                                                         \
  {                                                                          \
    __builtin_amdgcn_s_setprio(1);                                           \
    _Pragma("unroll") for (int mt = 0; mt < 4; ++mt)                         \
    _Pragma("unroll") for (int nt = 0; nt < 2; ++nt)                         \
    _Pragma("unroll") for (int kk = 0; kk < 2; ++kk)                         \
      acc[((mh) << 2) + mt][((nh) << 1) + nt] =                              \
          __builtin_amdgcn_mfma_f32_16x16x32_bf16(                           \
              aq[mt][kk], bq[((nh) << 1) + nt][kk],                          \
              acc[((mh) << 2) + mt][((nh) << 1) + nt], 0, 0, 0);             \
    __builtin_amdgcn_s_setprio(0);                                           \
  }

  CSTG(0, 0, 0); CSTG(0, 0, 1); CSTG(0, 0, 2); CSTG(0, 0, 3);
  CSTG(1, 1, 0); CSTG(1, 1, 1);
  BARV(2);

  for (int it = 0; it < 7; ++it) {
    const int k0 = 2 * it, k1 = 2 * it + 1, k2 = 2 * it + 2, k3 = 2 * it + 3;
    CLDA(k0, 0); CLDB(0, 0);
    CSTG(k1, 1, 2);
    CMMX(0, 0); BARX;
    CLDB(0, 1);
    CSTG(k1, 1, 3);
    CMMX(0, 1); BARX;
    CLDA(k0, 1);
    CSTG(k2, 0, 0);
    CMMX(1, 0); BARX;
    CSTG(k2, 0, 1);
    CMMX(1, 1); BARV(2);
    CLDA(k1, 0); CLDB(1, 0);
    CSTG(k2, 0, 2);
    CMMX(0, 0); BARX;
    CLDB(1, 1);
    CSTG(k2, 0, 3);
    CMMX(0, 1); BARX;
    CLDA(k1, 1);
    CSTG(k3, 1, 0);
    CMMX(1, 0); BARX;
    CSTG(k3, 1, 1);
    CMMX(1, 1); BARV(2);
  }
  CLDA(14, 0); CLDB(0, 0);
  CSTG(15, 1, 2);
  CMMX(0, 0); BARX;
  CLDB(0, 1);
  CSTG(15, 1, 3);
  CMMX(0, 1); BARX;
  CLDA(14, 1);
  CMMX(1, 0); BARX;
  CMMX(1, 1);
  BARV(0);
  CLDA(15, 0); CLDB(1, 0);
  CMMX(0, 0); BARX;
  CLDB(1, 1);
  CMMX(0, 1); BARX;
  CLDA(15, 1);
  CMMX(1, 0); BARX;
  CMMX(1, 1);
#undef CSTG
#undef CLDA
#undef CLDB
#undef CMMX

#pragma unroll
  for (int ai = 0; ai < 8; ++ai) {
    int i = m0 + wm + ((ai >> 2) << 7) + ((ai & 3) << 4) + (fq << 2);
#pragma unroll
    for (int nj = 0; nj < 4; ++nj) {
      int col = n0 + wn + ((nj >> 1) << 7) + ((nj & 1) << 4) + fm;
      int b = col >> 6, k = col & 63;
      size_t off = ((size_t)(b << 10) + i) * 768 + (h << 6) + k;
#pragma unroll
      for (int r = 0; r < 4; ++r) {
        float val = acc[ai][nj][r] + xin[off + (size_t)r * 768];
        x2bf[off + (size_t)r * 768] = f2bf(val);
      }
    }
  }
}

extern "C" void kernel_launch(void* const* d_in, const int* in_sizes, int n_in,
                              void* d_out, int out_size, void* d_ws, size_t ws_size,
                              hipStream_t stream) {
  const float* x = (const float*)d_in[0];
  const float* ln1_s = (const float*)d_in[1];
  const float* ln1_b = (const float*)d_in[2];
  const float* Wv = (const float*)d_in[3];
  const float* alpha = (const float*)d_in[4];
  const float* Wf = (const float*)d_in[5];
  const float* bf = (const float*)d_in[6];
  const float* lnf_s = (const float*)d_in[7];
  const float* lnf_b = (const float*)d_in[8];
  float* out = (float*)d_out;

  char* ws = (char*)d_ws;
  unsigned short* slotA = (unsigned short*)ws;
  unsigned short* Vt = (unsigned short*)(ws + 25165824);
  unsigned short* gbf = Vt;
  unsigned short* slotX = (unsigned short*)(ws + 50331648);
  unsigned short* W2t = (unsigned short*)(ws + 75497472);
  unsigned short* Wft = (unsigned short*)(ws + 76677120);

  hipFuncSetAttribute((const void*)gemm1_256,
                      hipFuncAttributeMaxDynamicSharedMemorySize, 131072);
  hipFuncSetAttribute((const void*)gemmf_256,
                      hipFuncAttributeMaxDynamicSharedMemorySize, 131072);
  hipFuncSetAttribute((const void*)circ256_kernel,
                      hipFuncAttributeMaxDynamicSharedMemorySize, 86144);

  // prelude: blocks 0..2303 pack W2t, 2304..6911 pack Wft, 6912..11007 ln1
  prelude_kernel<<<11008, 256, 0, stream>>>(Wv, Wf, W2t, Wft, x, ln1_s,
                                            ln1_b, slotA);
  gemm1_256<<<192, 512, 131072, stream>>>(slotA, W2t, Vt);
  circ256_kernel<<<192, 512, 86144, stream>>>(alpha, Vt, x, slotX);
  gemmf_256<<<192, 512, 131072, stream>>>(slotX, Wft, bf, gbf);
  lnswish_kernel<<<4096, 256, 0, stream>>>(gbf, lnf_s, lnf_b, slotA);
  gemmf_256<<<192, 512, 131072, stream>>>(slotA, Wft + 589824, bf + 768, gbf);
  final_kernel<<<4096, 256, 0, stream>>>(gbf, lnf_s + 768, lnf_b + 768, slotX, out);
}

// Round 11
// 261.966 us; speedup vs baseline: 1.0831x; 1.0223x over previous
//
#include <hip/hip_runtime.h>
#include <cstdint>
#include <cstddef>

// B=16, N=1024, D=768, H=12, HS=64, L=2
// R17 = R16 (best measured 267.8) with ONE change:
//  - circ256_kernel (45.2-45.8us measured) swapped back to the R6/R10
//    128² circ_kernel (41.1-41.7us measured in R4/R6/R10 profiles):
//    256 threads, 3 blocks/CU, 4-deep B pipeline, grid 768. Verbatim copy.
//  - Everything else byte-identical to R16.
//
// ws layout (bytes): unchanged.
//  [0, 25165824)          slotA : xn_bf16 -> z1_bf16
//  [25165824, 50331648)   Vt    : gemm1 out ; reused as gbf
//  [50331648, 75497472)   slotX : x2_bf16 (circ out)
//  [75497472, 76677120)   W2t
//  [76677120, 79036416)   Wft

typedef __attribute__((ext_vector_type(8))) short bf16x8;
typedef __attribute__((ext_vector_type(4))) float f32x4;
typedef __attribute__((ext_vector_type(4))) unsigned short us4;

__device__ __forceinline__ unsigned short f2bf(float f) {
  unsigned int u = __builtin_bit_cast(unsigned int, f);
  u += 0x7FFFu + ((u >> 16) & 1u);
  return (unsigned short)(u >> 16);
}
__device__ __forceinline__ float bf2f(unsigned short u) {
  return __builtin_bit_cast(float, (unsigned int)u << 16);
}

__device__ __forceinline__ void g2l16(const void* g, void* l) {
  __builtin_amdgcn_global_load_lds(
      (const __attribute__((address_space(1))) unsigned int*)g,
      (__attribute__((address_space(3))) unsigned int*)l,
      16, 0, 0);
}

#define WAITB(n) asm volatile("s_waitcnt vmcnt(" #n ") lgkmcnt(0)\n\ts_barrier" ::: "memory")
#define BARX asm volatile("s_waitcnt lgkmcnt(0)\n\ts_barrier" ::: "memory")
#define BARV(n) asm volatile("s_waitcnt vmcnt(" #n ") lgkmcnt(0)\n\ts_barrier" ::: "memory")

// ---------------- row-kernel helper ----------------
__device__ __forceinline__ void wave_reduce2(float& s, float& s2) {
#pragma unroll
  for (int off = 32; off > 0; off >>= 1) {
    s += __shfl_down(s, off);
    s2 += __shfl_down(s2, off);
  }
  s = __shfl(s, 0);
  s2 = __shfl(s2, 0);
}

// ---------------- prelude: weight pack (blocks 0..6911) + ln1 (6912..) ----
__global__ __launch_bounds__(256) void prelude_kernel(
    const float* __restrict__ Wv, const float* __restrict__ Wf,
    unsigned short* __restrict__ W2t, unsigned short* __restrict__ Wft,
    const float* __restrict__ x, const float* __restrict__ sc,
    const float* __restrict__ bi, unsigned short* __restrict__ xn) {
  int bid = blockIdx.x;
  if (bid < 2304) {
    int o = bid * 256 + threadIdx.x;
    int np = o / 768, d = o - np * 768;
    int h = np >> 6, k = np & 63;
    W2t[o] = f2bf(Wv[h * 49152 + d * 64 + k]);
    return;
  }
  if (bid < 6912) {
    int o = (bid - 2304) * 256 + threadIdx.x;
    int l = o / 589824, rem = o - l * 589824;
    int np = rem / 768, d = rem - np * 768;
    Wft[o] = f2bf(Wf[l * 589824 + d * 768 + np]);
    return;
  }
  // ln1: row kernel, 4 rows/block
  int row = (bid - 6912) * 4 + (threadIdx.x >> 6);
  int lane = threadIdx.x & 63;
  size_t base = (size_t)row * 768;
  float4 v[3];
#pragma unroll
  for (int j = 0; j < 3; ++j) v[j] = *(const float4*)(x + base + lane * 4 + j * 256);
  float s = 0.f, s2 = 0.f;
#pragma unroll
  for (int j = 0; j < 3; ++j) {
    s += v[j].x + v[j].y + v[j].z + v[j].w;
    s2 += v[j].x * v[j].x + v[j].y * v[j].y + v[j].z * v[j].z + v[j].w * v[j].w;
  }
  wave_reduce2(s, s2);
  float mu = s * (1.0f / 768.0f);
  float var = s2 * (1.0f / 768.0f) - mu * mu;
  float r = rsqrtf(var + 1e-6f);
#pragma unroll
  for (int j = 0; j < 3; ++j) {
    int d = lane * 4 + j * 256;
    float4 scv = *(const float4*)(sc + d);
    float4 biv = *(const float4*)(bi + d);
    us4 o;
    o[0] = f2bf((v[j].x - mu) * r * scv.x + biv.x);
    o[1] = f2bf((v[j].y - mu) * r * scv.y + biv.y);
    o[2] = f2bf((v[j].z - mu) * r * scv.z + biv.z);
    o[3] = f2bf((v[j].w - mu) * r * scv.w + biv.w);
    *(us4*)(xn + base + d) = o;
  }
}

__global__ __launch_bounds__(256) void lnswish_kernel(const unsigned short* __restrict__ g,
                                                      const float* __restrict__ sc,
                                                      const float* __restrict__ bi,
                                                      unsigned short* __restrict__ out) {
  int row = blockIdx.x * 4 + (threadIdx.x >> 6);
  int lane = threadIdx.x & 63;
  size_t base = (size_t)row * 768;
  float v[3][4];
#pragma unroll
  for (int j = 0; j < 3; ++j) {
    us4 gv = *(const us4*)(g + base + lane * 4 + j * 256);
#pragma unroll
    for (int q = 0; q < 4; ++q) v[j][q] = bf2f(gv[q]);
  }
  float s = 0.f, s2 = 0.f;
#pragma unroll
  for (int j = 0; j < 3; ++j)
#pragma unroll
    for (int q = 0; q < 4; ++q) { s += v[j][q]; s2 += v[j][q] * v[j][q]; }
  wave_reduce2(s, s2);
  float mu = s * (1.0f / 768.0f);
  float var = s2 * (1.0f / 768.0f) - mu * mu;
  float r = rsqrtf(var + 1e-6f);
#pragma unroll
  for (int j = 0; j < 3; ++j) {
    int d = lane * 4 + j * 256;
    float4 scv = *(const float4*)(sc + d);
    float4 biv = *(const float4*)(bi + d);
    const float* scp = &scv.x;
    const float* bip = &biv.x;
    us4 o;
#pragma unroll
    for (int q = 0; q < 4; ++q) {
      float z = (v[j][q] - mu) * r * scp[q] + bip[q];
      o[q] = f2bf(z / (1.0f + __expf(-z)));
    }
    *(us4*)(out + base + d) = o;
  }
}

__global__ __launch_bounds__(256) void final_kernel(const unsigned short* __restrict__ g,
                                                    const float* __restrict__ sc,
                                                    const float* __restrict__ bi,
                                                    const unsigned short* __restrict__ x2,
                                                    float* __restrict__ out) {
  int row = blockIdx.x * 4 + (threadIdx.x >> 6);
  int lane = threadIdx.x & 63;
  size_t base = (size_t)row * 768;
  float v[3][4];
#pragma unroll
  for (int j = 0; j < 3; ++j) {
    us4 gv = *(const us4*)(g + base + lane * 4 + j * 256);
#pragma unroll
    for (int q = 0; q < 4; ++q) v[j][q] = bf2f(gv[q]);
  }
  float s = 0.f, s2 = 0.f;
#pragma unroll
  for (int j = 0; j < 3; ++j)
#pragma unroll
    for (int q = 0; q < 4; ++q) { s += v[j][q]; s2 += v[j][q] * v[j][q]; }
  wave_reduce2(s, s2);
  float mu = s * (1.0f / 768.0f);
  float var = s2 * (1.0f / 768.0f) - mu * mu;
  float r = rsqrtf(var + 1e-6f);
#pragma unroll
  for (int j = 0; j < 3; ++j) {
    int d = lane * 4 + j * 256;
    float4 scv = *(const float4*)(sc + d);
    float4 biv = *(const float4*)(bi + d);
    us4 xv = *(const us4*)(x2 + base + d);
    const float* scp = &scv.x;
    const float* bip = &biv.x;
    float4 o;
    float* op = &o.x;
#pragma unroll
    for (int q = 0; q < 4; ++q) {
      float z = (v[j][q] - mu) * r * scp[q] + bip[q];
      float sw = z / (1.0f + __expf(-z));
      float t = sw + bf2f(xv[q]);
      float ax = fabsf(t);
      op[q] = ax + __logf(1.0f + __expf(-2.0f * ax)) - 0.69314718055994531f;
    }
    *(float4*)(out + base + d) = o;
  }
}

// ---------- 256x256 8-phase dense GEMM core (R8 verbatim) ----------
template <int K>
__device__ __forceinline__ void gemm256(const unsigned short* __restrict__ A,
                                        const unsigned short* __restrict__ Bt,
                                        int m0, int n0, unsigned short* lds,
                                        f32x4 acc[8][4]) {
  const int tid = threadIdx.x;
  const int lane = tid & 63;
  const int wid = tid >> 6;
  const int wm = (wid >> 2) << 6;
  const int wn = (wid & 3) << 5;
  const int fm = lane & 15, fq = lane >> 4;
  const int srow = tid >> 3;
  const int sslot = (tid & 7) ^ (srow & 7);
  const size_t abase = (size_t)(m0 + srow) * K + (sslot << 3);
  const size_t bbase = (size_t)(n0 + srow) * K + (sslot << 3);

  bf16x8 aq[4][2], bq[4][2];

#define STG_A(kt, bb, c)                                                     \
  g2l16(A + abase + (size_t)((c) << 6) * K + ((kt) << 6),                    \
        lds + ((bb) << 15) + ((c) << 12) + (tid << 3))
#define STG_B(kt, bb, c)                                                     \
  g2l16(Bt + bbase + (size_t)((c) << 6) * K + ((kt) << 6),                   \
        lds + ((bb) << 15) + 16384 + ((c) << 12) + (tid << 3))
#define LDA(bb, mh)                                                          \
  _Pragma("unroll") for (int mt = 0; mt < 4; ++mt) {                         \
    const unsigned short* p =                                                \
        lds + ((bb) << 15) + (wm + ((mh) << 7) + (mt << 4) + fm) * 64;       \
    _Pragma("unroll") for (int kk = 0; kk < 2; ++kk)                         \
      aq[mt][kk] = *(const bf16x8*)(p + ((((kk << 2) + fq) ^ (fm & 7)) << 3)); \
  }
#define LDB(bb, nh)                                                          \
  _Pragma("unroll") for (int nt = 0; nt < 2; ++nt) {                         \
    const unsigned short* p = lds + ((bb) << 15) + 16384 +                   \
                              (wn + ((nh) << 7) + (nt << 4) + fm) * 64;      \
    _Pragma("unroll") for (int kk = 0; kk < 2; ++kk)                         \
      bq[((nh) << 1) + nt][kk] =                                             \
          *(const bf16x8*)(p + ((((kk << 2) + fq) ^ (fm & 7)) << 3));        \
  }
#define MMX(mh, nh)                                                          \
  {                                                                          \
    __builtin_amdgcn_s_setprio(1);                                           \
    _Pragma("unroll") for (int mt = 0; mt < 4; ++mt)                         \
    _Pragma("unroll") for (int nt = 0; nt < 2; ++nt)                         \
    _Pragma("unroll") for (int kk = 0; kk < 2; ++kk)                         \
      acc[((mh) << 2) + mt][((nh) << 1) + nt] =                              \
          __builtin_amdgcn_mfma_f32_16x16x32_bf16(                           \
              aq[mt][kk], bq[((nh) << 1) + nt][kk],                          \
              acc[((mh) << 2) + mt][((nh) << 1) + nt], 0, 0, 0);             \
    __builtin_amdgcn_s_setprio(0);                                           \
  }

  constexpr int NT = K >> 6;
  STG_A(0, 0, 0); STG_A(0, 0, 1); STG_A(0, 0, 2); STG_A(0, 0, 3);
  STG_B(0, 0, 0); STG_B(0, 0, 1); STG_B(0, 0, 2); STG_B(0, 0, 3);
  STG_A(1, 1, 0); STG_A(1, 1, 1);
  STG_B(1, 1, 0); STG_B(1, 1, 1);
  BARV(4);

  for (int t = 0; t < (NT >> 1) - 1; ++t) {
    const int k1 = 2 * t + 1, k2 = 2 * t + 2, k3 = 2 * t + 3;
    LDA(0, 0); LDB(0, 0);
    STG_A(k1, 1, 2); STG_A(k1, 1, 3);
    MMX(0, 0); BARX;
    LDB(0, 1);
    STG_B(k1, 1, 2); STG_B(k1, 1, 3);
    MMX(0, 1); BARX;
    LDA(0, 1);
    STG_A(k2, 0, 0); STG_A(k2, 0, 1);
    MMX(1, 0); BARX;
    STG_B(k2, 0, 0); STG_B(k2, 0, 1);
    MMX(1, 1); BARV(4);
    LDA(1, 0); LDB(1, 0);
    STG_A(k2, 0, 2); STG_A(k2, 0, 3);
    MMX(0, 0); BARX;
    LDB(1, 1);
    STG_B(k2, 0, 2); STG_B(k2, 0, 3);
    MMX(0, 1); BARX;
    LDA(1, 1);
    STG_A(k3, 1, 0); STG_A(k3, 1, 1);
    MMX(1, 0); BARX;
    STG_B(k3, 1, 0); STG_B(k3, 1, 1);
    MMX(1, 1); BARV(4);
  }
  {
    const int k1 = NT - 1;
    LDA(0, 0); LDB(0, 0);
    STG_A(k1, 1, 2); STG_A(k1, 1, 3);
    MMX(0, 0); BARX;
    LDB(0, 1);
    STG_B(k1, 1, 2); STG_B(k1, 1, 3);
    MMX(0, 1); BARX;
    LDA(0, 1);
    MMX(1, 0); BARX;
    MMX(1, 1);
    BARV(0);
    LDA(1, 0); LDB(1, 0);
    MMX(0, 0); BARX;
    LDB(1, 1);
    MMX(0, 1); BARX;
    LDA(1, 1);
    MMX(1, 0); BARX;
    MMX(1, 1);
  }
#undef STG_A
#undef STG_B
#undef LDA
#undef LDB
#undef MMX
}

__device__ __forceinline__ void decode256(int bid, int& m0, int& n0) {
  int wg = (bid & 7) * 24 + (bid >> 3);
  int mi = wg / 3, ni = wg - mi * 3;
  m0 = mi << 8;
  n0 = ni << 8;
}

// GEMM1: xn @ W2t -> Vt[h][b*64+k][n] (bf16)
__global__ __launch_bounds__(512, 2) void gemm1_256(const unsigned short* __restrict__ A,
                                                    const unsigned short* __restrict__ W2t,
                                                    unsigned short* __restrict__ Vt) {
  extern __shared__ unsigned short lds[];
  f32x4 acc[8][4] = {};
  int m0, n0;
  decode256(blockIdx.x, m0, n0);
  gemm256<768>(A, W2t, m0, n0, lds, acc);
  const int lane = threadIdx.x & 63, wid = threadIdx.x >> 6;
  const int wm = (wid >> 2) << 6, wn = (wid & 3) << 5;
  const int fm = lane & 15, fq = lane >> 4;
#pragma unroll
  for (int ai = 0; ai < 8; ++ai) {
    int rowb = m0 + wm + ((ai >> 2) << 7) + ((ai & 3) << 4) + (fq << 2);
    int b = rowb >> 10, n = rowb & 1023;
#pragma unroll
    for (int nj = 0; nj < 4; ++nj) {
      int col = n0 + wn + ((nj >> 1) << 7) + ((nj & 1) << 4) + fm;
      int h = col >> 6, ck = col & 63;
      size_t off = ((size_t)h << 20) + (size_t)((b << 6) + ck) * 1024 + n;
      us4 v;
#pragma unroll
      for (int r = 0; r < 4; ++r) v[r] = f2bf(acc[ai][nj][r]);
      *(us4*)(Vt + off) = v;
    }
  }
}

// FFN GEMM: A(bf16) @ Wt + bias -> g (bf16)
__global__ __launch_bounds__(512, 2) void gemmf_256(const unsigned short* __restrict__ A,
                                                    const unsigned short* __restrict__ Bt,
                                                    const float* __restrict__ bias,
                                                    unsigned short* __restrict__ g) {
  extern __shared__ unsigned short lds[];
  f32x4 acc[8][4] = {};
  int m0, n0;
  decode256(blockIdx.x, m0, n0);
  gemm256<768>(A, Bt, m0, n0, lds, acc);
  const int lane = threadIdx.x & 63, wid = threadIdx.x >> 6;
  const int wm = (wid >> 2) << 6, wn = (wid & 3) << 5;
  const int fm = lane & 15, fq = lane >> 4;
#pragma unroll
  for (int ai = 0; ai < 8; ++ai) {
    int rowb = m0 + wm + ((ai >> 2) << 7) + ((ai & 3) << 4) + (fq << 2);
#pragma unroll
    for (int nj = 0; nj < 4; ++nj) {
      int col = n0 + wn + ((nj >> 1) << 7) + ((nj & 1) << 4) + fm;
      float bc = bias[col];
#pragma unroll
      for (int r = 0; r < 4; ++r)
        g[(size_t)(rowb + r) * 768 + col] = f2bf(acc[ai][nj][r] + bc);
    }
  }
}

// circGEMM (R6/R10 verbatim, measured 41.1-41.7us): A from alpha (circulant,
// LDS shifted copies), B = Vt_h, 4-deep B pipeline, depth-3, 256 threads,
// 3 blocks/CU. epilogue: x2 = x + y (bf16).
__global__ __launch_bounds__(256, 3) void circ_kernel(const float* __restrict__ alpha,
                                                      const unsigned short* __restrict__ Vt,
                                                      const float* __restrict__ xin,
                                                      unsigned short* __restrict__ x2bf) {
  __shared__ unsigned short sAc[8 * 1168];   // 8 shift-copies of alpha window
  __shared__ unsigned short sB[4 * 4096];    // 4-deep B pipeline
  f32x4 acc[4][4] = {};
  int f = blockIdx.x;
  int xcd = f & 7, s = f >> 3;
  int h = s >> 3, t = s & 7;
  int mr = xcd >> 1, nr = xcd & 1;
  int m0 = ((mr << 1) + (t >> 2)) << 7;
  int n0 = ((nr << 2) + (t & 3)) << 7;

  const int tid = threadIdx.x;
  const int wave = tid >> 6, lane = tid & 63;
  const int wm = (wave >> 1) << 6, wn = (wave & 1) << 6;
  const int fm = lane & 15, fq = lane >> 4;

  const float* ah = alpha + (h << 10);
#pragma unroll
  for (int c = 0; c < 8; ++c)
    for (int u = tid; u < 1160; u += 256)
      sAc[c * 1168 + u] = f2bf(ah[(m0 - 897 - u - c) & 1023]);
  asm volatile("s_waitcnt vmcnt(0)" ::: "memory");  // flush fill loads from vmcnt

  const unsigned short* Bt = Vt + ((size_t)h << 20);
  const int r0 = tid >> 2, r1 = r0 + 64;
  const int cg = tid & 3;
  const int cs0 = (cg ^ ((r0 >> 1) & 3)) << 3;
  const int cs1 = (cg ^ ((r1 >> 1) & 3)) << 3;
  const int ld0 = r0 * 32 + (cg << 3);
  const int ld1 = r1 * 32 + (cg << 3);

#define STAGEB(k0v, buf)                                                      \
  {                                                                           \
    unsigned short* dB = sB + (buf) * 4096;                                   \
    g2l16(Bt + (size_t)(n0 + r0) * 1024 + (k0v) + cs0, dB + ld0);             \
    g2l16(Bt + (size_t)(n0 + r1) * 1024 + (k0v) + cs1, dB + ld1);             \
  }
#define CCOMP(it)                                                             \
  {                                                                           \
    const unsigned short* pB = sB + ((it) & 3) * 4096;                        \
    int k0v = (it) << 5;                                                      \
    bf16x8 aq[4], bq[4];                                                      \
    _Pragma("unroll") for (int t_ = 0; t_ < 4; ++t_) {                        \
      int rl = wm + (t_ << 4) + fm;                                           \
      int d = k0v + (fq << 3) + 127 - rl;                                     \
      int c = d & 7;                                                          \
      aq[t_] = *(const bf16x8*)(sAc + c * 1168 + (d - c));                    \
      int rb = wn + (t_ << 4) + fm;                                           \
      bq[t_] = *(const bf16x8*)(pB + (rb << 5) + ((fq ^ ((rb >> 1) & 3)) << 3)); \
    }                                                                         \
    _Pragma("unroll") for (int mt = 0; mt < 4; ++mt)                          \
    _Pragma("unroll") for (int nt = 0; nt < 4; ++nt)                          \
      acc[mt][nt] = __builtin_amdgcn_mfma_f32_16x16x32_bf16(aq[mt], bq[nt],   \
                                                            acc[mt][nt], 0, 0, 0); \
  }

  STAGEB(0, 0);
  STAGEB(32, 1);
  STAGEB(64, 2);
  for (int it = 0; it < 30; ++it) {
    WAITB(4);                     // stage(it) landed; it+1, it+2 in flight
    if (it < 29) STAGEB((it + 3) << 5, (it + 3) & 3);
    CCOMP(it);
  }
  WAITB(2);
  CCOMP(30);
  WAITB(0);
  CCOMP(31);
#undef STAGEB

  // epilogue: x2 = x + y (bf16)
#pragma unroll
  for (int mt = 0; mt < 4; ++mt) {
    int ib = m0 + wm + (mt << 4) + (fq << 2);
#pragma unroll
    for (int nt = 0; nt < 4; ++nt) {
      int c = n0 + wn + (nt << 4) + fm;
      int b = c >> 6, k = c & 63;
      size_t off = ((size_t)(b << 10) + ib) * 768 + (h << 6) + k;
#pragma unroll
      for (int r = 0; r < 4; ++r) {
        float val = acc[mt][nt][r] + xin[off + (size_t)r * 768];
        x2bf[off + (size_t)r * 768] = f2bf(val);
      }
    }
  }
}

extern "C" void kernel_launch(void* const* d_in, const int* in_sizes, int n_in,
                              void* d_out, int out_size, void* d_ws, size_t ws_size,
                              hipStream_t stream) {
  const float* x = (const float*)d_in[0];
  const float* ln1_s = (const float*)d_in[1];
  const float* ln1_b = (const float*)d_in[2];
  const float* Wv = (const float*)d_in[3];
  const float* alpha = (const float*)d_in[4];
  const float* Wf = (const float*)d_in[5];
  const float* bf = (const float*)d_in[6];
  const float* lnf_s = (const float*)d_in[7];
  const float* lnf_b = (const float*)d_in[8];
  float* out = (float*)d_out;

  char* ws = (char*)d_ws;
  unsigned short* slotA = (unsigned short*)ws;
  unsigned short* Vt = (unsigned short*)(ws + 25165824);
  unsigned short* gbf = Vt;
  unsigned short* slotX = (unsigned short*)(ws + 50331648);
  unsigned short* W2t = (unsigned short*)(ws + 75497472);
  unsigned short* Wft = (unsigned short*)(ws + 76677120);

  hipFuncSetAttribute((const void*)gemm1_256,
                      hipFuncAttributeMaxDynamicSharedMemorySize, 131072);
  hipFuncSetAttribute((const void*)gemmf_256,
                      hipFuncAttributeMaxDynamicSharedMemorySize, 131072);

  // prelude: blocks 0..2303 pack W2t, 2304..6911 pack Wft, 6912..11007 ln1
  prelude_kernel<<<11008, 256, 0, stream>>>(Wv, Wf, W2t, Wft, x, ln1_s,
                                            ln1_b, slotA);
  gemm1_256<<<192, 512, 131072, stream>>>(slotA, W2t, Vt);
  circ_kernel<<<768, 256, 0, stream>>>(alpha, Vt, x, slotX);
  gemmf_256<<<192, 512, 131072, stream>>>(slotX, Wft, bf, gbf);
  lnswish_kernel<<<4096, 256, 0, stream>>>(gbf, lnf_s, lnf_b, slotA);
  gemmf_256<<<192, 512, 131072, stream>>>(slotA, Wft + 589824, bf + 768, gbf);
  final_kernel<<<4096, 256, 0, stream>>>(gbf, lnf_s + 768, lnf_b + 768, slotX, out);
}